// Round 4
// baseline (375.700 us; speedup 1.0000x reference)
//
#include <hip/hip_runtime.h>
#include <hip/hip_bf16.h>

#define DI __device__ __forceinline__

#if __has_builtin(__builtin_amdgcn_exp2f)
#define EXP2(x) __builtin_amdgcn_exp2f(x)
#else
#define EXP2(x) exp2f(x)
#endif

namespace {

constexpr int Bc = 2, Tc = 2048, Dc = 2048, Hc = 32, KVHc = 8, HDc = 64;
constexpr int NQKV = Hc * HDc + 2 * KVHc * HDc;  // 3072

typedef __bf16 bf16x8 __attribute__((ext_vector_type(8)));
typedef unsigned short u16x8 __attribute__((ext_vector_type(8)));
typedef unsigned short u16x4 __attribute__((ext_vector_type(4)));
typedef float f32x4 __attribute__((ext_vector_type(4)));

union FragU { u16x8 u; bf16x8 b; u16x4 h[2]; };

DI float bits2f(unsigned int u) {
  union { unsigned int i; float f; } v; v.i = u << 16; return v.f;
}
DI unsigned short f2bits(float f) {
  __hip_bfloat16 h = __float2bfloat16(f);
  return *reinterpret_cast<unsigned short*>(&h);
}

DI void store_out(float* p, float v) { *p = v; }
DI void store_out(__hip_bfloat16* p, float v) { *p = __float2bfloat16(v); }

typedef __attribute__((address_space(1))) void gv_t;
typedef __attribute__((address_space(3))) void lv_t;

// Stage TOTB bytes (tile rows of ROWB bytes, global row stride row_stride_b) into
// LDS via global_load_lds width=16. LDS dest is wave-uniform base + lane*16 (HW),
// so the optional XOR swizzle permutes the GLOBAL source chunk per lane instead:
// LDS slot (row, chunk k) holds global chunk k ^ (row&7)  [ROWB=128 only].
template<int ROWB, int TOTB, bool SWZ = false>
DI void stage_tile(const char* g, long long row_stride_b, char* lds) {
  const int tid = threadIdx.x;
  const int wid = tid >> 6, lane = tid & 63;
#pragma unroll
  for (int it = 0; it < TOTB / 4096; ++it) {
    int off = it * 4096 + wid * 1024 + lane * 16;
    int row = off / ROWB;
    int colb = off % ROWB;
    if (SWZ) colb ^= (row & 7) << 4;  // 16B-chunk XOR swizzle (ROWB=128)
    const char* gp = g + (long long)row * row_stride_b + colb;
    char* lp = lds + it * 4096 + wid * 1024;  // wave-uniform
    __builtin_amdgcn_global_load_lds((gv_t*)gp, (lv_t*)lp, 16, 0, 0);
  }
}

// ---------------- f32 -> bf16 elementwise convert (8 elems/thread) ----------------
__global__ __launch_bounds__(256) void cvt_f32_bf16(
    const float* __restrict__ in, __hip_bfloat16* __restrict__ out) {
  const long long i = ((long long)blockIdx.x * 256 + threadIdx.x) * 8;
  const float4 a = *(const float4*)(in + i);
  const float4 b = *(const float4*)(in + i + 4);
  u16x8 r;
  r[0] = f2bits(a.x); r[1] = f2bits(a.y); r[2] = f2bits(a.z); r[3] = f2bits(a.w);
  r[4] = f2bits(b.x); r[5] = f2bits(b.y); r[6] = f2bits(b.z); r[7] = f2bits(b.w);
  *(u16x8*)((unsigned short*)out + i) = r;
}

// ------------- 64x64 tiled transpose + f32->bf16 convert: out[c][r] = in[r][c] -------------
__global__ __launch_bounds__(256) void transpose_cvt_kernel(
    const float* __restrict__ in, __hip_bfloat16* __restrict__ out, int R, int C) {
  __shared__ unsigned short tile[64][65];
  const int c0 = blockIdx.x * 64, r0 = blockIdx.y * 64;
  const int tid = threadIdx.x;
  const int rr = tid >> 2, seg = (tid & 3) * 16;
  const float* src = in + (long long)(r0 + rr) * C + c0 + seg;
#pragma unroll
  for (int i = 0; i < 16; ++i) tile[rr][seg + i] = f2bits(src[i]);
  __syncthreads();
  unsigned short* dst = (unsigned short*)out + (long long)(c0 + rr) * R + r0 + seg;
#pragma unroll
  for (int i = 0; i < 16; ++i) dst[i] = tile[seg + i][rr];
}

// ---------------- 64x64 tiled bf16 transpose: out[c][r] = in[r][c] ----------------
__global__ __launch_bounds__(256) void transpose_kernel(
    const __hip_bfloat16* __restrict__ in, __hip_bfloat16* __restrict__ out,
    int R, int C) {
  __shared__ unsigned short tile[64][65];
  const long long slice = (long long)R * C;
  const unsigned short* ip = (const unsigned short*)in + (long long)blockIdx.z * slice;
  unsigned short* op = (unsigned short*)out + (long long)blockIdx.z * slice;
  const int c0 = blockIdx.x * 64, r0 = blockIdx.y * 64;
  const int tid = threadIdx.x;
  const int rr = tid >> 2, seg = (tid & 3) * 16;
  const unsigned short* src = ip + (long long)(r0 + rr) * C + c0 + seg;
#pragma unroll
  for (int i = 0; i < 16; ++i) tile[rr][seg + i] = src[i];
  __syncthreads();
  unsigned short* dst = op + (long long)(c0 + rr) * R + r0 + seg;
#pragma unroll
  for (int i = 0; i < 16; ++i) dst[i] = tile[seg + i][rr];
}

// ---------------- GEMM: C[m][n] = sum_k A[m][k]*Bt[n][k] (+bias[n]) ----------------
// A: MxK row-major bf16, Bt: NxK row-major bf16 (B pre-transposed), C: MxN (OT).
// 128x128 tile, BK=32, 4 waves in 2x2, 4x4 16x16x32 MFMAs per wave. (round-3/4 validated)
template <typename OT>
__global__ __launch_bounds__(256) void gemm_bt(
    const __hip_bfloat16* __restrict__ A, const __hip_bfloat16* __restrict__ Bt,
    const float* __restrict__ bias, OT* __restrict__ C, int M, int N, int K) {
  __shared__ __align__(16) char As[8192];  // 128 x 32 bf16
  __shared__ __align__(16) char Bs[8192];
  const int n0 = blockIdx.x * 128;
  const int m0 = blockIdx.y * 128;
  const int tid = threadIdx.x;
  const int wid = tid >> 6, lane = tid & 63;
  const int wm = (wid >> 1) * 64, wn = (wid & 1) * 64;
  const int l15 = lane & 15, quad = lane >> 4;

  f32x4 acc[4][4] = {};

  const int nk = K >> 5;
  for (int kt = 0; kt < nk; ++kt) {
    __syncthreads();  // protect LDS reuse from previous iteration's readers
    stage_tile<64, 8192>((const char*)(A + (long long)m0 * K + kt * 32), (long long)K * 2, As);
    stage_tile<64, 8192>((const char*)(Bt + (long long)n0 * K + kt * 32), (long long)K * 2, Bs);
    __syncthreads();  // drains vmcnt(0): staging complete

    FragU a[4], b[4];
#pragma unroll
    for (int mt = 0; mt < 4; ++mt)
      a[mt].u = *(const u16x8*)(As + ((wm + mt * 16 + l15) * 32 + quad * 8) * 2);
#pragma unroll
    for (int nt = 0; nt < 4; ++nt)
      b[nt].u = *(const u16x8*)(Bs + ((wn + nt * 16 + l15) * 32 + quad * 8) * 2);
#pragma unroll
    for (int mt = 0; mt < 4; ++mt)
#pragma unroll
      for (int nt = 0; nt < 4; ++nt)
        acc[mt][nt] = __builtin_amdgcn_mfma_f32_16x16x32_bf16(a[mt].b, b[nt].b, acc[mt][nt], 0, 0, 0);
  }

#pragma unroll
  for (int nt = 0; nt < 4; ++nt) {
    const int col = n0 + wn + nt * 16 + l15;
    const float bv = bias ? bias[col] : 0.f;
#pragma unroll
    for (int mt = 0; mt < 4; ++mt) {
#pragma unroll
      for (int r = 0; r < 4; ++r) {
        const int row = m0 + wm + mt * 16 + quad * 4 + r;
        store_out(C + (long long)row * N + col, acc[mt][nt][r] + bv);
      }
    }
  }
}

// ---------------- RoPE + reshape (vectorized: one 16B chunk per thread) ----------------
// qkv (B*T, 3072) bf16 -> Q (B,H,T,64) roped*SCL, K (B,KVH,T,64) roped, V raw.
// SCL = (1/sqrt(64)) * log2(e) folded into Q so attention uses exp2.
// 384 threads/block, one row per block; thread t handles elems [8t, 8t+8) = 4 rope pairs.
__global__ __launch_bounds__(384) void rope_reshape(
    const __hip_bfloat16* __restrict__ qkv, const float* __restrict__ cosb,
    const float* __restrict__ sinb, __hip_bfloat16* __restrict__ Qo,
    __hip_bfloat16* __restrict__ Ko, __hip_bfloat16* __restrict__ Vo) {
  constexpr float SCL = 0.125f * 1.44269504088896f;
  const int row = blockIdx.x;            // b*T + t
  const int b = row / Tc, t = row % Tc;
  const unsigned short* src = (const unsigned short*)qkv + (long long)row * NQKV;
  const float* cb = cosb + t * 32;
  const float* sb = sinb + t * 32;
  const int e = (int)threadIdx.x * 8;    // 0..3064, section boundaries are multiples of 8
  const u16x8 v = *(const u16x8*)(src + e);
  if (e < Hc * HDc) {                         // Q section (scaled)
    const int hh = e >> 6, d = e & 63, ii = d >> 1;
    u16x8 r;
#pragma unroll
    for (int p = 0; p < 4; ++p) {
      const float c = cb[ii + p], s = sb[ii + p];
      const float xe = bits2f(v[2 * p]), xo = bits2f(v[2 * p + 1]);
      r[2 * p] = f2bits((xe * c - xo * s) * SCL);
      r[2 * p + 1] = f2bits((xe * s + xo * c) * SCL);
    }
    const long long idx = (((long long)b * Hc + hh) * Tc + t) * HDc + d;
    *(u16x8*)((unsigned short*)Qo + idx) = r;
  } else if (e < Hc * HDc + KVHc * HDc) {     // K section
    const int e2 = e - Hc * HDc;
    const int kh = e2 >> 6, d = e2 & 63, ii = d >> 1;
    u16x8 r;
#pragma unroll
    for (int p = 0; p < 4; ++p) {
      const float c = cb[ii + p], s = sb[ii + p];
      const float xe = bits2f(v[2 * p]), xo = bits2f(v[2 * p + 1]);
      r[2 * p] = f2bits(xe * c - xo * s);
      r[2 * p + 1] = f2bits(xe * s + xo * c);
    }
    const long long idx = (((long long)b * KVHc + kh) * Tc + t) * HDc + d;
    *(u16x8*)((unsigned short*)Ko + idx) = r;
  } else {                                    // V section (no rope)
    const int e2 = e - (Hc * HDc + KVHc * HDc);
    const int kh = e2 >> 6, d = e2 & 63;
    const long long idx = (((long long)b * KVHc + kh) * Tc + t) * HDc + d;
    *(u16x8*)((unsigned short*)Vo + idx) = v;
  }
}

// One kv-tile of flash attention for one q-state (round-6-proven body, verbatim).
// S^T = mfma(K_rows, Q_rows); zero-shuffle PV (kv<->k permuted identically on both
// operands); base-2 online softmax with in-lane reduce + 2 cross-quad shuffles.
DI void attn_tile(const char* __restrict__ Ksb, const char* __restrict__ Vsb,
                  const FragU (&qa)[2], f32x4 (&O)[4], float& m_i, float& l_i,
                  bool diag, int wid, int l15, int quad, int sw) {
  // S^T strip (64 kv x 16 q): S[nt][r] has kv = nt*16+quad*4+r, q = wid*16+l15
  f32x4 S[4] = {};
#pragma unroll
  for (int nt = 0; nt < 4; ++nt) {
#pragma unroll
    for (int ks = 0; ks < 2; ++ks) {
      FragU kb;
      kb.u = *(const u16x8*)(Ksb + (nt * 16 + l15) * 128 + ((((ks << 2) | quad) ^ sw) << 4));
      S[nt] = __builtin_amdgcn_mfma_f32_16x16x32_bf16(kb.b, qa[ks].b, S[nt], 0, 0, 0);
    }
  }

  // causal mask (wave-uniform; diagonal tile only; tile-local coords)
  if (diag) {
#pragma unroll
    for (int nt = 0; nt < 4; ++nt)
#pragma unroll
      for (int r = 0; r < 4; ++r)
        if ((nt * 16 + quad * 4 + r) > (wid * 16 + l15)) S[nt][r] = -1e30f;
  }

  // online softmax (base 2)
  float mx = fmaxf(fmaxf(S[0][0], S[0][1]), fmaxf(S[0][2], S[0][3]));
#pragma unroll
  for (int nt = 1; nt < 4; ++nt)
    mx = fmaxf(mx, fmaxf(fmaxf(S[nt][0], S[nt][1]), fmaxf(S[nt][2], S[nt][3])));
  mx = fmaxf(mx, __shfl_xor(mx, 16, 64));
  mx = fmaxf(mx, __shfl_xor(mx, 32, 64));
  const float mnew = fmaxf(m_i, mx);
  const float alpha = EXP2(m_i - mnew);  // first tile: exp2(-inf) = 0
  m_i = mnew;

  float pe[4][4];
  float sum = 0.f;
#pragma unroll
  for (int nt = 0; nt < 4; ++nt)
#pragma unroll
    for (int r = 0; r < 4; ++r) {
      const float p = EXP2(S[nt][r] - mnew);
      pe[nt][r] = p;
      sum += p;
    }
  sum += __shfl_xor(sum, 16, 64);
  sum += __shfl_xor(sum, 32, 64);
  l_i = l_i * alpha + sum;

  // pack P in-register (zero-shuffle: position (quad,j) holds kv=(2ks+(j>>2))*16+quad*4+(j&3))
  FragU pa[2];
#pragma unroll
  for (int ks = 0; ks < 2; ++ks)
#pragma unroll
    for (int r = 0; r < 4; ++r) {
      pa[ks].u[r] = f2bits(pe[2 * ks][r]);
      pa[ks].u[4 + r] = f2bits(pe[2 * ks + 1][r]);
    }
#pragma unroll
  for (int nt = 0; nt < 4; ++nt)
#pragma unroll
    for (int r = 0; r < 4; ++r) O[nt][r] *= alpha;

  // PV with the permuted-k mapping: A-frag (nt,ks) = two 8B chunks at 16B-chunk
  // indices g0 = ks*4+(quad>>1) and g0+2; byte (quad&1)*8.
#pragma unroll
  for (int nt = 0; nt < 4; ++nt) {
    const char* vrow = Vsb + (nt * 16 + l15) * 128 + ((quad & 1) << 3);
    const int gq = quad >> 1;
#pragma unroll
    for (int ks = 0; ks < 2; ++ks) {
      FragU vb;
      vb.h[0] = *(const u16x4*)(vrow + (((ks * 4 + gq) ^ sw) << 4));
      vb.h[1] = *(const u16x4*)(vrow + (((ks * 4 + gq + 2) ^ sw) << 4));
      O[nt] = __builtin_amdgcn_mfma_f32_16x16x32_bf16(vb.b, pa[ks].b, O[nt], 0, 0, 0);
    }
  }
}

// ------------- Causal flash attention, paired q-tiles + 2-phase K/V pipeline -------------
// Q (B,H,T,64) pre-scaled by 0.125*log2e, K (B,KVH,T,64), Vt (B,KVH,64,T) -> Out (B,T,H*64).
// Block p handles q-tiles A=p, B=31-p: uniform 33 kv-tiles/block (round-7-proven balance);
// K/V staged once per j, consumed by both q-states.
// Round-8 change: (1) Q fragments loaded DIRECTLY from global into registers (the LDS
// swizzle cancels: value chunk = ks*4+quad of the q row) -> no Qs buffers, no pending-
// ds_read-vs-overwrite hazard (the round-5 bug). (2) K/V double-buffered; iteration j
// issues stage(j+1) into buf^1, computes tile j from buf, then EXPLICIT
// s_waitcnt vmcnt(0) + one barrier. Prefetch latency hides under the 16-32 MFMAs +
// softmax of the current tile. Cross-wave visibility is guaranteed by the explicit
// drain (each wave's global_load_lds retires its vmcnt only after the LDS write lands).
__global__ __launch_bounds__(256, 4) void attn_kernel(
    const __hip_bfloat16* __restrict__ Q, const __hip_bfloat16* __restrict__ K,
    const __hip_bfloat16* __restrict__ Vt, __hip_bfloat16* __restrict__ Out) {
  __shared__ __align__(16) char Ks[2][8192];  // 64 kv x 64 hd (swizzled), double-buffered
  __shared__ __align__(16) char Vs[2][8192];  // 64 hd x 64 kv (swizzled), double-buffered

  const int p = blockIdx.x;                       // pair id 0..15
  const int qtA = p, qtB = (Tc / 64 - 1) - p;     // 31 - p
  const int h = blockIdx.y, b = blockIdx.z;
  const int kvh = h >> 2;  // G = 4
  const int tid = threadIdx.x, wid = tid >> 6, lane = tid & 63;
  const int l15 = lane & 15, quad = lane >> 4;
  const int sw = l15 & 7;

  const char* QgA = (const char*)(Q + (((long long)b * Hc + h) * Tc + qtA * 64) * HDc);
  const char* QgB = (const char*)(Q + (((long long)b * Hc + h) * Tc + qtB * 64) * HDc);
  const char* Kg = (const char*)(K + (((long long)b * KVHc + kvh) * Tc) * HDc);
  const char* Vg = (const char*)(Vt + (((long long)b * KVHc + kvh) * HDc) * Tc);

  // Q fragments straight from global: lane reads row (wid*16+l15), 16B chunk (ks*4+quad).
  FragU qaA[2], qaB[2];
#pragma unroll
  for (int ks = 0; ks < 2; ++ks) {
    const int qoff = (wid * 16 + l15) * 128 + (((ks << 2) | quad) << 4);
    qaA[ks].u = *(const u16x8*)(QgA + qoff);
    qaB[ks].u = *(const u16x8*)(QgB + qoff);
  }

  f32x4 OA[4] = {}, OB[4] = {};
  float mA = -1e30f, lA = 0.f, mB = -1e30f, lB = 0.f;

  // Prologue: stage tile 0 into buffer 0.
  stage_tile<128, 8192, true>(Kg, 128, Ks[0]);
  stage_tile<128, 8192, true>(Vg, (long long)Tc * 2, Vs[0]);
  asm volatile("s_waitcnt vmcnt(0)" ::: "memory");
  __syncthreads();

  for (int j = 0; j <= qtB; ++j) {
    const int cur = j & 1;
    // Prefetch next tile into the other buffer (its previous contents were last
    // read in iteration j-1, released by that iteration's end barrier).
    if (j < qtB) {
      stage_tile<128, 8192, true>(Kg + (long long)(j + 1) * 8192, 128, Ks[cur ^ 1]);
      stage_tile<128, 8192, true>(Vg + (long long)(j + 1) * 128, (long long)Tc * 2, Vs[cur ^ 1]);
    }

    attn_tile(Ks[cur], Vs[cur], qaB, OB, mB, lB, j == qtB, wid, l15, quad, sw);
    if (j <= qtA)  // wave-uniform: A's kv range is a prefix of B's
      attn_tile(Ks[cur], Vs[cur], qaA, OA, mA, lA, j == qtA, wid, l15, quad, sw);

    asm volatile("s_waitcnt vmcnt(0)" ::: "memory");  // my prefetch landed in LDS
    __syncthreads();                                  // everyone's landed; buf[cur] released
  }

  // epilogue x2: O^T / l -> Out[b][t][h*64+hd]; r-contiguous -> 8B stores
  const float invA = 1.0f / lA, invB = 1.0f / lB;
  const int tA = qtA * 64 + wid * 16 + l15;
  const int tB = qtB * 64 + wid * 16 + l15;
  unsigned short* obA =
      (unsigned short*)Out + ((long long)b * Tc + tA) * Dc + h * 64 + quad * 4;
  unsigned short* obB =
      (unsigned short*)Out + ((long long)b * Tc + tB) * Dc + h * 64 + quad * 4;
#pragma unroll
  for (int nt = 0; nt < 4; ++nt) {
    u16x4 va, vb;
#pragma unroll
    for (int r = 0; r < 4; ++r) {
      va[r] = f2bits(OA[nt][r] * invA);
      vb[r] = f2bits(OB[nt][r] * invB);
    }
    *(u16x4*)(obA + nt * 16) = va;
    *(u16x4*)(obB + nt * 16) = vb;
  }
}

}  // namespace

extern "C" void kernel_launch(void* const* d_in, const int* in_sizes, int n_in,
                              void* d_out, int out_size, void* d_ws, size_t ws_size,
                              hipStream_t stream) {
  // All inputs/outputs are FLOAT32 per the reference dtypes.
  const float* x_q  = (const float*)d_in[0];
  const float* Wqkv = (const float*)d_in[1];
  const float* Wout = (const float*)d_in[2];
  const float* bout = (const float*)d_in[3];
  const float* rc   = (const float*)d_in[4];
  const float* rs   = (const float*)d_in[5];
  float* out = (float*)d_out;

  // ---- Overlapping bf16 workspace arena (peak 54.6 MB; stream order makes reuse safe) ----
  constexpr size_t SZ_QKV   = (size_t)Bc * Tc * NQKV * 2;        // 25,165,824
  constexpr size_t SZ_XB    = (size_t)Bc * Tc * Dc * 2;          // 16,777,216
  constexpr size_t SZ_QB    = (size_t)Bc * Hc * Tc * HDc * 2;    // 16,777,216
  constexpr size_t SZ_KV    = (size_t)Bc * KVHc * Tc * HDc * 2;  //  4,194,304
  constexpr size_t SZ_AO    = (size_t)Bc * Tc * Dc * 2;          // 16,777,216
  constexpr size_t OFF_QKV   = 0;                    //  0   .. 25.2M
  constexpr size_t OFF_XB    = SZ_QKV;               // 25.2 .. 41.9M
  constexpr size_t OFF_WQKVT = SZ_QKV + SZ_XB;       // 41.9 .. 54.6M
  constexpr size_t OFF_QB    = SZ_QKV;               // reuses xb (dead after G1)
  constexpr size_t OFF_KB    = OFF_QB + SZ_QB;       // reuses WqkvT head (dead after G1)
  constexpr size_t OFF_VTMP  = OFF_KB + SZ_KV;       // 46.1 .. 50.3M
  constexpr size_t OFF_VT    = 0;                    // reuses qkv (dead after R)
  constexpr size_t OFF_AO    = SZ_KV;                // 4.2 .. 21.0M (old qkv region)
  constexpr size_t OFF_WOUTT = OFF_AO + SZ_AO;       // 21.0 .. 29.4M (old Qb head, dead after A)

  char* w = (char*)d_ws;
  __hip_bfloat16* qkv   = (__hip_bfloat16*)(w + OFF_QKV);
  __hip_bfloat16* xb    = (__hip_bfloat16*)(w + OFF_XB);
  __hip_bfloat16* WqkvT = (__hip_bfloat16*)(w + OFF_WQKVT);
  __hip_bfloat16* Qb    = (__hip_bfloat16*)(w + OFF_QB);
  __hip_bfloat16* Kb    = (__hip_bfloat16*)(w + OFF_KB);
  __hip_bfloat16* Vtmp  = (__hip_bfloat16*)(w + OFF_VTMP);
  __hip_bfloat16* Vt    = (__hip_bfloat16*)(w + OFF_VT);
  __hip_bfloat16* AO    = (__hip_bfloat16*)(w + OFF_AO);
  __hip_bfloat16* WoutT = (__hip_bfloat16*)(w + OFF_WOUTT);

  // C1: x_q f32 -> bf16
  cvt_f32_bf16<<<dim3((Bc * Tc * Dc) / (256 * 8)), 256, 0, stream>>>(x_q, xb);

  // T1: W_qkv (D,3072) f32 -> (3072,D) bf16
  transpose_cvt_kernel<<<dim3(NQKV / 64, Dc / 64), 256, 0, stream>>>(Wqkv, WqkvT, Dc, NQKV);

  // G1: qkv = x @ W_qkv  (bf16 out)
  gemm_bt<__hip_bfloat16><<<dim3(NQKV / 128, (Bc * Tc) / 128), 256, 0, stream>>>(
      xb, WqkvT, nullptr, qkv, Bc * Tc, NQKV, Dc);

  // R: split + rope (+ Q pre-scale) + head-major layouts (384 thr = 3072/8 chunks)
  rope_reshape<<<dim3(Bc * Tc), 384, 0, stream>>>(qkv, rc, rs, Qb, Kb, Vtmp);

  // TV: V (B,KVH,T,64) -> V^T (B,KVH,64,T)
  transpose_kernel<<<dim3(HDc / 64, Tc / 64, Bc * KVHc), 256, 0, stream>>>(Vtmp, Vt, Tc, HDc);

  // A: flash attention (paired q-tiles, 2-phase K/V pipeline)
  attn_kernel<<<dim3(Tc / 128, Hc, Bc), 256, 0, stream>>>(Qb, Kb, Vt, AO);

  // T2: W_out f32 -> W_out^T bf16
  transpose_cvt_kernel<<<dim3(Dc / 64, Dc / 64), 256, 0, stream>>>(Wout, WoutT, Dc, Dc);

  // G2: out = AO @ W_out + b_out  (f32 out)
  gemm_bt<float><<<dim3(Dc / 128, (Bc * Tc) / 128), 256, 0, stream>>>(
      AO, WoutT, bout, out, Bc * Tc, Dc, Dc);
}

// Round 5
// 349.861 us; speedup vs baseline: 1.0739x; 1.0739x over previous
//
#include <hip/hip_runtime.h>
#include <hip/hip_bf16.h>

#define DI __device__ __forceinline__

#if __has_builtin(__builtin_amdgcn_exp2f)
#define EXP2(x) __builtin_amdgcn_exp2f(x)
#else
#define EXP2(x) exp2f(x)
#endif

namespace {

constexpr int Bc = 2, Tc = 2048, Dc = 2048, Hc = 32, KVHc = 8, HDc = 64;
constexpr int NQKV = Hc * HDc + 2 * KVHc * HDc;  // 3072

typedef __bf16 bf16x8 __attribute__((ext_vector_type(8)));
typedef unsigned short u16x8 __attribute__((ext_vector_type(8)));
typedef unsigned short u16x4 __attribute__((ext_vector_type(4)));
typedef float f32x4 __attribute__((ext_vector_type(4)));

union FragU { u16x8 u; bf16x8 b; u16x4 h[2]; };

DI float bits2f(unsigned int u) {
  union { unsigned int i; float f; } v; v.i = u << 16; return v.f;
}
DI unsigned short f2bits(float f) {
  __hip_bfloat16 h = __float2bfloat16(f);
  return *reinterpret_cast<unsigned short*>(&h);
}

DI void store_out(float* p, float v) { *p = v; }
DI void store_out(__hip_bfloat16* p, float v) { *p = __float2bfloat16(v); }

typedef __attribute__((address_space(1))) void gv_t;
typedef __attribute__((address_space(3))) void lv_t;

// Stage TOTB bytes (tile rows of ROWB bytes, global row stride row_stride_b) into
// LDS via global_load_lds width=16. LDS dest is wave-uniform base + lane*16 (HW),
// so the optional XOR swizzle permutes the GLOBAL source chunk per lane instead:
// LDS slot (row, chunk k) holds global chunk k ^ (row&7)  [ROWB=128 only].
template<int ROWB, int TOTB, bool SWZ = false>
DI void stage_tile(const char* g, long long row_stride_b, char* lds) {
  const int tid = threadIdx.x;
  const int wid = tid >> 6, lane = tid & 63;
#pragma unroll
  for (int it = 0; it < TOTB / 4096; ++it) {
    int off = it * 4096 + wid * 1024 + lane * 16;
    int row = off / ROWB;
    int colb = off % ROWB;
    if (SWZ) colb ^= (row & 7) << 4;  // 16B-chunk XOR swizzle (ROWB=128)
    const char* gp = g + (long long)row * row_stride_b + colb;
    char* lp = lds + it * 4096 + wid * 1024;  // wave-uniform
    __builtin_amdgcn_global_load_lds((gv_t*)gp, (lv_t*)lp, 16, 0, 0);
  }
}

// ---------------- f32 -> bf16 elementwise convert (8 elems/thread) ----------------
__global__ __launch_bounds__(256) void cvt_f32_bf16(
    const float* __restrict__ in, __hip_bfloat16* __restrict__ out) {
  const long long i = ((long long)blockIdx.x * 256 + threadIdx.x) * 8;
  const float4 a = *(const float4*)(in + i);
  const float4 b = *(const float4*)(in + i + 4);
  u16x8 r;
  r[0] = f2bits(a.x); r[1] = f2bits(a.y); r[2] = f2bits(a.z); r[3] = f2bits(a.w);
  r[4] = f2bits(b.x); r[5] = f2bits(b.y); r[6] = f2bits(b.z); r[7] = f2bits(b.w);
  *(u16x8*)((unsigned short*)out + i) = r;
}

// ------------- 64x64 tiled transpose + f32->bf16 convert: out[c][r] = in[r][c] -------------
__global__ __launch_bounds__(256) void transpose_cvt_kernel(
    const float* __restrict__ in, __hip_bfloat16* __restrict__ out, int R, int C) {
  __shared__ unsigned short tile[64][65];
  const int c0 = blockIdx.x * 64, r0 = blockIdx.y * 64;
  const int tid = threadIdx.x;
  const int rr = tid >> 2, seg = (tid & 3) * 16;
  const float* src = in + (long long)(r0 + rr) * C + c0 + seg;
#pragma unroll
  for (int i = 0; i < 16; ++i) tile[rr][seg + i] = f2bits(src[i]);
  __syncthreads();
  unsigned short* dst = (unsigned short*)out + (long long)(c0 + rr) * R + r0 + seg;
#pragma unroll
  for (int i = 0; i < 16; ++i) dst[i] = tile[seg + i][rr];
}

// ---------------- 64x64 tiled bf16 transpose: out[c][r] = in[r][c] ----------------
__global__ __launch_bounds__(256) void transpose_kernel(
    const __hip_bfloat16* __restrict__ in, __hip_bfloat16* __restrict__ out,
    int R, int C) {
  __shared__ unsigned short tile[64][65];
  const long long slice = (long long)R * C;
  const unsigned short* ip = (const unsigned short*)in + (long long)blockIdx.z * slice;
  unsigned short* op = (unsigned short*)out + (long long)blockIdx.z * slice;
  const int c0 = blockIdx.x * 64, r0 = blockIdx.y * 64;
  const int tid = threadIdx.x;
  const int rr = tid >> 2, seg = (tid & 3) * 16;
  const unsigned short* src = ip + (long long)(r0 + rr) * C + c0 + seg;
#pragma unroll
  for (int i = 0; i < 16; ++i) tile[rr][seg + i] = src[i];
  __syncthreads();
  unsigned short* dst = op + (long long)(c0 + rr) * R + r0 + seg;
#pragma unroll
  for (int i = 0; i < 16; ++i) dst[i] = tile[seg + i][rr];
}

// ---------------- GEMM: C[m][n] = sum_k A[m][k]*Bt[n][k] (+bias[n]) ----------------
// A: MxK row-major bf16, Bt: NxK row-major bf16 (B pre-transposed), C: MxN (OT).
// 128x128 tile, BK=32, 4 waves in 2x2, 4x4 16x16x32 MFMAs per wave. (round-3/4 validated)
template <typename OT>
__global__ __launch_bounds__(256) void gemm_bt(
    const __hip_bfloat16* __restrict__ A, const __hip_bfloat16* __restrict__ Bt,
    const float* __restrict__ bias, OT* __restrict__ C, int M, int N, int K) {
  __shared__ __align__(16) char As[8192];  // 128 x 32 bf16
  __shared__ __align__(16) char Bs[8192];
  const int n0 = blockIdx.x * 128;
  const int m0 = blockIdx.y * 128;
  const int tid = threadIdx.x;
  const int wid = tid >> 6, lane = tid & 63;
  const int wm = (wid >> 1) * 64, wn = (wid & 1) * 64;
  const int l15 = lane & 15, quad = lane >> 4;

  f32x4 acc[4][4] = {};

  const int nk = K >> 5;
  for (int kt = 0; kt < nk; ++kt) {
    __syncthreads();  // protect LDS reuse from previous iteration's readers
    stage_tile<64, 8192>((const char*)(A + (long long)m0 * K + kt * 32), (long long)K * 2, As);
    stage_tile<64, 8192>((const char*)(Bt + (long long)n0 * K + kt * 32), (long long)K * 2, Bs);
    __syncthreads();  // drains vmcnt(0): staging complete

    FragU a[4], b[4];
#pragma unroll
    for (int mt = 0; mt < 4; ++mt)
      a[mt].u = *(const u16x8*)(As + ((wm + mt * 16 + l15) * 32 + quad * 8) * 2);
#pragma unroll
    for (int nt = 0; nt < 4; ++nt)
      b[nt].u = *(const u16x8*)(Bs + ((wn + nt * 16 + l15) * 32 + quad * 8) * 2);
#pragma unroll
    for (int mt = 0; mt < 4; ++mt)
#pragma unroll
      for (int nt = 0; nt < 4; ++nt)
        acc[mt][nt] = __builtin_amdgcn_mfma_f32_16x16x32_bf16(a[mt].b, b[nt].b, acc[mt][nt], 0, 0, 0);
  }

#pragma unroll
  for (int nt = 0; nt < 4; ++nt) {
    const int col = n0 + wn + nt * 16 + l15;
    const float bv = bias ? bias[col] : 0.f;
#pragma unroll
    for (int mt = 0; mt < 4; ++mt) {
#pragma unroll
      for (int r = 0; r < 4; ++r) {
        const int row = m0 + wm + mt * 16 + quad * 4 + r;
        store_out(C + (long long)row * N + col, acc[mt][nt][r] + bv);
      }
    }
  }
}

// ---------------- RoPE + reshape (vectorized: one 16B chunk per thread) ----------------
// qkv (B*T, 3072) bf16 -> Q (B,H,T,64) roped*SCL, K (B,KVH,T,64) roped, V raw.
// SCL = (1/sqrt(64)) * log2(e) folded into Q so attention uses exp2.
// 384 threads/block, one row per block; thread t handles elems [8t, 8t+8) = 4 rope pairs.
__global__ __launch_bounds__(384) void rope_reshape(
    const __hip_bfloat16* __restrict__ qkv, const float* __restrict__ cosb,
    const float* __restrict__ sinb, __hip_bfloat16* __restrict__ Qo,
    __hip_bfloat16* __restrict__ Ko, __hip_bfloat16* __restrict__ Vo) {
  constexpr float SCL = 0.125f * 1.44269504088896f;
  const int row = blockIdx.x;            // b*T + t
  const int b = row / Tc, t = row % Tc;
  const unsigned short* src = (const unsigned short*)qkv + (long long)row * NQKV;
  const float* cb = cosb + t * 32;
  const float* sb = sinb + t * 32;
  const int e = (int)threadIdx.x * 8;    // 0..3064, section boundaries are multiples of 8
  const u16x8 v = *(const u16x8*)(src + e);
  if (e < Hc * HDc) {                         // Q section (scaled)
    const int hh = e >> 6, d = e & 63, ii = d >> 1;
    u16x8 r;
#pragma unroll
    for (int p = 0; p < 4; ++p) {
      const float c = cb[ii + p], s = sb[ii + p];
      const float xe = bits2f(v[2 * p]), xo = bits2f(v[2 * p + 1]);
      r[2 * p] = f2bits((xe * c - xo * s) * SCL);
      r[2 * p + 1] = f2bits((xe * s + xo * c) * SCL);
    }
    const long long idx = (((long long)b * Hc + hh) * Tc + t) * HDc + d;
    *(u16x8*)((unsigned short*)Qo + idx) = r;
  } else if (e < Hc * HDc + KVHc * HDc) {     // K section
    const int e2 = e - Hc * HDc;
    const int kh = e2 >> 6, d = e2 & 63, ii = d >> 1;
    u16x8 r;
#pragma unroll
    for (int p = 0; p < 4; ++p) {
      const float c = cb[ii + p], s = sb[ii + p];
      const float xe = bits2f(v[2 * p]), xo = bits2f(v[2 * p + 1]);
      r[2 * p] = f2bits(xe * c - xo * s);
      r[2 * p + 1] = f2bits(xe * s + xo * c);
    }
    const long long idx = (((long long)b * KVHc + kh) * Tc + t) * HDc + d;
    *(u16x8*)((unsigned short*)Ko + idx) = r;
  } else {                                    // V section (no rope)
    const int e2 = e - (Hc * HDc + KVHc * HDc);
    const int kh = e2 >> 6, d = e2 & 63;
    const long long idx = (((long long)b * KVHc + kh) * Tc + t) * HDc + d;
    *(u16x8*)((unsigned short*)Vo + idx) = v;
  }
}

// ---------------- attention helpers (round-6-proven math, refactored) ----------------
// Layouts: S^T strip: S[nt][r] has kv = nt*16+quad*4+r, q = wid*16+l15.
// Zero-shuffle PV: kv <-> mfma-k remapped identically on both operands as
// k = quad*8+j <-> kv = (2ks+(j>>2))*16 + quad*4 + (j&3).

DI void mask_diag(f32x4 (&S)[4], int wid, int l15, int quad) {
#pragma unroll
  for (int nt = 0; nt < 4; ++nt)
#pragma unroll
    for (int r = 0; r < 4; ++r)
      if ((nt * 16 + quad * 4 + r) > (wid * 16 + l15)) S[nt][r] = -1e30f;
}

// Online-softmax update (base 2): consumes S in place (becomes p), returns alpha,
// updates m,l, and packs the PV B-fragments (lane-local, zero data movement).
DI float softmax_pack(f32x4 (&S)[4], float& m_i, float& l_i, FragU (&pa)[2]) {
  float mx = fmaxf(fmaxf(S[0][0], S[0][1]), fmaxf(S[0][2], S[0][3]));
#pragma unroll
  for (int nt = 1; nt < 4; ++nt)
    mx = fmaxf(mx, fmaxf(fmaxf(S[nt][0], S[nt][1]), fmaxf(S[nt][2], S[nt][3])));
  mx = fmaxf(mx, __shfl_xor(mx, 16, 64));
  mx = fmaxf(mx, __shfl_xor(mx, 32, 64));
  const float mnew = fmaxf(m_i, mx);
  const float alpha = EXP2(m_i - mnew);  // first tile: exp2(-inf) = 0
  m_i = mnew;
  float sum = 0.f;
#pragma unroll
  for (int nt = 0; nt < 4; ++nt)
#pragma unroll
    for (int r = 0; r < 4; ++r) {
      const float pp = EXP2(S[nt][r] - mnew);
      S[nt][r] = pp;
      sum += pp;
    }
  sum += __shfl_xor(sum, 16, 64);
  sum += __shfl_xor(sum, 32, 64);
  l_i = l_i * alpha + sum;
#pragma unroll
  for (int ks = 0; ks < 2; ++ks)
#pragma unroll
    for (int r = 0; r < 4; ++r) {
      pa[ks].u[r] = f2bits(S[2 * ks][r]);
      pa[ks].u[4 + r] = f2bits(S[2 * ks + 1][r]);
    }
  return alpha;
}

// Single-state kv-tile (used when only q-state B is in causal range).
DI void attn_tile(const char* __restrict__ Ksb, const char* __restrict__ Vsb,
                  const FragU (&qa)[2], f32x4 (&O)[4], float& m_i, float& l_i,
                  bool diag, int wid, int l15, int quad, int sw) {
  f32x4 S[4] = {};
  __builtin_amdgcn_s_setprio(1);
#pragma unroll
  for (int nt = 0; nt < 4; ++nt) {
#pragma unroll
    for (int ks = 0; ks < 2; ++ks) {
      FragU kb;
      kb.u = *(const u16x8*)(Ksb + (nt * 16 + l15) * 128 + ((((ks << 2) | quad) ^ sw) << 4));
      S[nt] = __builtin_amdgcn_mfma_f32_16x16x32_bf16(kb.b, qa[ks].b, S[nt], 0, 0, 0);
    }
  }
  __builtin_amdgcn_s_setprio(0);
  if (diag) mask_diag(S, wid, l15, quad);
  FragU pa[2];
  const float alpha = softmax_pack(S, m_i, l_i, pa);
#pragma unroll
  for (int nt = 0; nt < 4; ++nt)
#pragma unroll
    for (int r = 0; r < 4; ++r) O[nt][r] *= alpha;
  __builtin_amdgcn_s_setprio(1);
#pragma unroll
  for (int nt = 0; nt < 4; ++nt) {
    const char* vrow = Vsb + (nt * 16 + l15) * 128 + ((quad & 1) << 3);
    const int gq = quad >> 1;
#pragma unroll
    for (int ks = 0; ks < 2; ++ks) {
      FragU vb;
      vb.h[0] = *(const u16x4*)(vrow + (((ks * 4 + gq) ^ sw) << 4));
      vb.h[1] = *(const u16x4*)(vrow + (((ks * 4 + gq + 2) ^ sw) << 4));
      O[nt] = __builtin_amdgcn_mfma_f32_16x16x32_bf16(vb.b, pa[ks].b, O[nt], 0, 0, 0);
    }
  }
  __builtin_amdgcn_s_setprio(0);
}

// DUAL-state kv-tile (round-9): both q-states share every K/V fragment read
// (halves LDS traffic) and provide two independent dependence chains -> the
// scheduler pairs back-to-back MFMAs and overlaps the two softmax chains.
// B is never diagonal on the dual path (qtB > qtA always).
DI void attn_tile_dual(const char* __restrict__ Ksb, const char* __restrict__ Vsb,
                       const FragU (&qaB)[2], const FragU (&qaA)[2],
                       f32x4 (&OB)[4], f32x4 (&OA)[4],
                       float& mB, float& lB, float& mA, float& lA,
                       bool diagA, int wid, int l15, int quad, int sw) {
  f32x4 SB[4] = {}, SA[4] = {};
  __builtin_amdgcn_s_setprio(1);
#pragma unroll
  for (int nt = 0; nt < 4; ++nt) {
#pragma unroll
    for (int ks = 0; ks < 2; ++ks) {
      FragU kb;
      kb.u = *(const u16x8*)(Ksb + (nt * 16 + l15) * 128 + ((((ks << 2) | quad) ^ sw) << 4));
      SB[nt] = __builtin_amdgcn_mfma_f32_16x16x32_bf16(kb.b, qaB[ks].b, SB[nt], 0, 0, 0);
      SA[nt] = __builtin_amdgcn_mfma_f32_16x16x32_bf16(kb.b, qaA[ks].b, SA[nt], 0, 0, 0);
    }
  }
  __builtin_amdgcn_s_setprio(0);
  if (diagA) mask_diag(SA, wid, l15, quad);
  FragU paB[2], paA[2];
  const float aB = softmax_pack(SB, mB, lB, paB);
  const float aA = softmax_pack(SA, mA, lA, paA);
#pragma unroll
  for (int nt = 0; nt < 4; ++nt)
#pragma unroll
    for (int r = 0; r < 4; ++r) {
      OB[nt][r] *= aB;
      OA[nt][r] *= aA;
    }
  __builtin_amdgcn_s_setprio(1);
#pragma unroll
  for (int nt = 0; nt < 4; ++nt) {
    const char* vrow = Vsb + (nt * 16 + l15) * 128 + ((quad & 1) << 3);
    const int gq = quad >> 1;
#pragma unroll
    for (int ks = 0; ks < 2; ++ks) {
      FragU vb;
      vb.h[0] = *(const u16x4*)(vrow + (((ks * 4 + gq) ^ sw) << 4));
      vb.h[1] = *(const u16x4*)(vrow + (((ks * 4 + gq + 2) ^ sw) << 4));
      OB[nt] = __builtin_amdgcn_mfma_f32_16x16x32_bf16(vb.b, paB[ks].b, OB[nt], 0, 0, 0);
      OA[nt] = __builtin_amdgcn_mfma_f32_16x16x32_bf16(vb.b, paA[ks].b, OA[nt], 0, 0, 0);
    }
  }
  __builtin_amdgcn_s_setprio(0);
}

// ------------- Causal flash attention, paired q-tiles + dual-state interleave -------------
// Q (B,H,T,64) pre-scaled by 0.125*log2e, K (B,KVH,T,64), Vt (B,KVH,64,T) -> Out (B,T,H*64).
// Block p handles q-tiles A=p, B=31-p: uniform 33 kv-tiles/block (round-7 balance).
// Q fragments direct from global (swizzle cancels; round-8). K/V double-buffered with
// top-of-loop prefetch + explicit vmcnt(0) drain + one barrier per tile (round-8).
// Round-9: dual-state fused tile on j <= qtA (shared K/V frags, two independent chains).
__global__ __launch_bounds__(256, 4) void attn_kernel(
    const __hip_bfloat16* __restrict__ Q, const __hip_bfloat16* __restrict__ K,
    const __hip_bfloat16* __restrict__ Vt, __hip_bfloat16* __restrict__ Out) {
  __shared__ __align__(16) char Ks[2][8192];  // 64 kv x 64 hd (swizzled), double-buffered
  __shared__ __align__(16) char Vs[2][8192];  // 64 hd x 64 kv (swizzled), double-buffered

  const int p = blockIdx.x;                       // pair id 0..15
  const int qtA = p, qtB = (Tc / 64 - 1) - p;     // 31 - p
  const int h = blockIdx.y, b = blockIdx.z;
  const int kvh = h >> 2;  // G = 4
  const int tid = threadIdx.x, wid = tid >> 6, lane = tid & 63;
  const int l15 = lane & 15, quad = lane >> 4;
  const int sw = l15 & 7;

  const char* QgA = (const char*)(Q + (((long long)b * Hc + h) * Tc + qtA * 64) * HDc);
  const char* QgB = (const char*)(Q + (((long long)b * Hc + h) * Tc + qtB * 64) * HDc);
  const char* Kg = (const char*)(K + (((long long)b * KVHc + kvh) * Tc) * HDc);
  const char* Vg = (const char*)(Vt + (((long long)b * KVHc + kvh) * HDc) * Tc);

  // Q fragments straight from global: lane reads row (wid*16+l15), 16B chunk (ks*4+quad).
  FragU qaA[2], qaB[2];
#pragma unroll
  for (int ks = 0; ks < 2; ++ks) {
    const int qoff = (wid * 16 + l15) * 128 + (((ks << 2) | quad) << 4);
    qaA[ks].u = *(const u16x8*)(QgA + qoff);
    qaB[ks].u = *(const u16x8*)(QgB + qoff);
  }

  f32x4 OA[4] = {}, OB[4] = {};
  float mA = -1e30f, lA = 0.f, mB = -1e30f, lB = 0.f;

  // Prologue: stage tile 0 into buffer 0.
  stage_tile<128, 8192, true>(Kg, 128, Ks[0]);
  stage_tile<128, 8192, true>(Vg, (long long)Tc * 2, Vs[0]);
  asm volatile("s_waitcnt vmcnt(0)" ::: "memory");
  __syncthreads();

  for (int j = 0; j <= qtB; ++j) {
    const int cur = j & 1;
    // Prefetch next tile into the other buffer (released by last iter's barrier).
    if (j < qtB) {
      stage_tile<128, 8192, true>(Kg + (long long)(j + 1) * 8192, 128, Ks[cur ^ 1]);
      stage_tile<128, 8192, true>(Vg + (long long)(j + 1) * 128, (long long)Tc * 2, Vs[cur ^ 1]);
    }

    if (j <= qtA) {  // wave-uniform: A's kv range is a prefix of B's
      attn_tile_dual(Ks[cur], Vs[cur], qaB, qaA, OB, OA, mB, lB, mA, lA,
                     j == qtA, wid, l15, quad, sw);
    } else {
      attn_tile(Ks[cur], Vs[cur], qaB, OB, mB, lB, j == qtB, wid, l15, quad, sw);
    }

    asm volatile("s_waitcnt vmcnt(0)" ::: "memory");  // my prefetch landed in LDS
    __syncthreads();                                  // everyone's landed; buf[cur] released
  }

  // epilogue x2: O^T / l -> Out[b][t][h*64+hd]; r-contiguous -> 8B stores
  const float invA = 1.0f / lA, invB = 1.0f / lB;
  const int tA = qtA * 64 + wid * 16 + l15;
  const int tB = qtB * 64 + wid * 16 + l15;
  unsigned short* obA =
      (unsigned short*)Out + ((long long)b * Tc + tA) * Dc + h * 64 + quad * 4;
  unsigned short* obB =
      (unsigned short*)Out + ((long long)b * Tc + tB) * Dc + h * 64 + quad * 4;
#pragma unroll
  for (int nt = 0; nt < 4; ++nt) {
    u16x4 va, vb;
#pragma unroll
    for (int r = 0; r < 4; ++r) {
      va[r] = f2bits(OA[nt][r] * invA);
      vb[r] = f2bits(OB[nt][r] * invB);
    }
    *(u16x4*)(obA + nt * 16) = va;
    *(u16x4*)(obB + nt * 16) = vb;
  }
}

}  // namespace

extern "C" void kernel_launch(void* const* d_in, const int* in_sizes, int n_in,
                              void* d_out, int out_size, void* d_ws, size_t ws_size,
                              hipStream_t stream) {
  // All inputs/outputs are FLOAT32 per the reference dtypes.
  const float* x_q  = (const float*)d_in[0];
  const float* Wqkv = (const float*)d_in[1];
  const float* Wout = (const float*)d_in[2];
  const float* bout = (const float*)d_in[3];
  const float* rc   = (const float*)d_in[4];
  const float* rs   = (const float*)d_in[5];
  float* out = (float*)d_out;

  // ---- Overlapping bf16 workspace arena (peak 54.6 MB; stream order makes reuse safe) ----
  constexpr size_t SZ_QKV   = (size_t)Bc * Tc * NQKV * 2;        // 25,165,824
  constexpr size_t SZ_XB    = (size_t)Bc * Tc * Dc * 2;          // 16,777,216
  constexpr size_t SZ_QB    = (size_t)Bc * Hc * Tc * HDc * 2;    // 16,777,216
  constexpr size_t SZ_KV    = (size_t)Bc * KVHc * Tc * HDc * 2;  //  4,194,304
  constexpr size_t SZ_AO    = (size_t)Bc * Tc * Dc * 2;          // 16,777,216
  constexpr size_t OFF_QKV   = 0;                    //  0   .. 25.2M
  constexpr size_t OFF_XB    = SZ_QKV;               // 25.2 .. 41.9M
  constexpr size_t OFF_WQKVT = SZ_QKV + SZ_XB;       // 41.9 .. 54.6M
  constexpr size_t OFF_QB    = SZ_QKV;               // reuses xb (dead after G1)
  constexpr size_t OFF_KB    = OFF_QB + SZ_QB;       // reuses WqkvT head (dead after G1)
  constexpr size_t OFF_VTMP  = OFF_KB + SZ_KV;       // 46.1 .. 50.3M
  constexpr size_t OFF_VT    = 0;                    // reuses qkv (dead after R)
  constexpr size_t OFF_AO    = SZ_KV;                // 4.2 .. 21.0M (old qkv region)
  constexpr size_t OFF_WOUTT = OFF_AO + SZ_AO;       // 21.0 .. 29.4M (old Qb head, dead after A)

  char* w = (char*)d_ws;
  __hip_bfloat16* qkv   = (__hip_bfloat16*)(w + OFF_QKV);
  __hip_bfloat16* xb    = (__hip_bfloat16*)(w + OFF_XB);
  __hip_bfloat16* WqkvT = (__hip_bfloat16*)(w + OFF_WQKVT);
  __hip_bfloat16* Qb    = (__hip_bfloat16*)(w + OFF_QB);
  __hip_bfloat16* Kb    = (__hip_bfloat16*)(w + OFF_KB);
  __hip_bfloat16* Vtmp  = (__hip_bfloat16*)(w + OFF_VTMP);
  __hip_bfloat16* Vt    = (__hip_bfloat16*)(w + OFF_VT);
  __hip_bfloat16* AO    = (__hip_bfloat16*)(w + OFF_AO);
  __hip_bfloat16* WoutT = (__hip_bfloat16*)(w + OFF_WOUTT);

  // C1: x_q f32 -> bf16
  cvt_f32_bf16<<<dim3((Bc * Tc * Dc) / (256 * 8)), 256, 0, stream>>>(x_q, xb);

  // T1: W_qkv (D,3072) f32 -> (3072,D) bf16
  transpose_cvt_kernel<<<dim3(NQKV / 64, Dc / 64), 256, 0, stream>>>(Wqkv, WqkvT, Dc, NQKV);

  // G1: qkv = x @ W_qkv  (bf16 out)
  gemm_bt<__hip_bfloat16><<<dim3(NQKV / 128, (Bc * Tc) / 128), 256, 0, stream>>>(
      xb, WqkvT, nullptr, qkv, Bc * Tc, NQKV, Dc);

  // R: split + rope (+ Q pre-scale) + head-major layouts (384 thr = 3072/8 chunks)
  rope_reshape<<<dim3(Bc * Tc), 384, 0, stream>>>(qkv, rc, rs, Qb, Kb, Vtmp);

  // TV: V (B,KVH,T,64) -> V^T (B,KVH,64,T)
  transpose_kernel<<<dim3(HDc / 64, Tc / 64, Bc * KVHc), 256, 0, stream>>>(Vtmp, Vt, Tc, HDc);

  // A: flash attention (paired q-tiles, dual-state interleave, 2-phase K/V pipeline)
  attn_kernel<<<dim3(Tc / 128, Hc, Bc), 256, 0, stream>>>(Qb, Kb, Vt, AO);

  // T2: W_out f32 -> W_out^T bf16
  transpose_cvt_kernel<<<dim3(Dc / 64, Dc / 64), 256, 0, stream>>>(Wout, WoutT, Dc, Dc);

  // G2: out = AO @ W_out + b_out  (f32 out)
  gemm_bt<float><<<dim3(Dc / 128, (Bc * Tc) / 128), 256, 0, stream>>>(
      AO, WoutT, bout, out, Bc * Tc, Dc, Dc);
}

// Round 6
// 330.642 us; speedup vs baseline: 1.1363x; 1.0581x over previous
//
#include <hip/hip_runtime.h>
#include <hip/hip_bf16.h>

#define DI __device__ __forceinline__

#if __has_builtin(__builtin_amdgcn_exp2f)
#define EXP2(x) __builtin_amdgcn_exp2f(x)
#else
#define EXP2(x) exp2f(x)
#endif

namespace {

constexpr int Bc = 2, Tc = 2048, Dc = 2048, Hc = 32, KVHc = 8, HDc = 64;
constexpr int NQKV = Hc * HDc + 2 * KVHc * HDc;  // 3072

typedef __bf16 bf16x8 __attribute__((ext_vector_type(8)));
typedef unsigned short u16x8 __attribute__((ext_vector_type(8)));
typedef unsigned short u16x4 __attribute__((ext_vector_type(4)));
typedef float f32x4 __attribute__((ext_vector_type(4)));

union FragU { u16x8 u; bf16x8 b; u16x4 h[2]; };

DI float bits2f(unsigned int u) {
  union { unsigned int i; float f; } v; v.i = u << 16; return v.f;
}
DI unsigned short f2bits(float f) {
  __hip_bfloat16 h = __float2bfloat16(f);
  return *reinterpret_cast<unsigned short*>(&h);
}

DI void store_out(float* p, float v) { *p = v; }
DI void store_out(__hip_bfloat16* p, float v) { *p = __float2bfloat16(v); }

typedef __attribute__((address_space(1))) void gv_t;
typedef __attribute__((address_space(3))) void lv_t;

// Stage TOTB bytes (tile rows of ROWB bytes, global row stride row_stride_b) into
// LDS via global_load_lds width=16. LDS dest is wave-uniform base + lane*16 (HW),
// so the optional XOR swizzle permutes the GLOBAL source chunk per lane instead:
// LDS slot (row, chunk k) holds global chunk k ^ (row&7)  [ROWB=128 only].
template<int ROWB, int TOTB, bool SWZ = false>
DI void stage_tile(const char* g, long long row_stride_b, char* lds) {
  const int tid = threadIdx.x;
  const int wid = tid >> 6, lane = tid & 63;
#pragma unroll
  for (int it = 0; it < TOTB / 4096; ++it) {
    int off = it * 4096 + wid * 1024 + lane * 16;
    int row = off / ROWB;
    int colb = off % ROWB;
    if (SWZ) colb ^= (row & 7) << 4;  // 16B-chunk XOR swizzle (ROWB=128)
    const char* gp = g + (long long)row * row_stride_b + colb;
    char* lp = lds + it * 4096 + wid * 1024;  // wave-uniform
    __builtin_amdgcn_global_load_lds((gv_t*)gp, (lv_t*)lp, 16, 0, 0);
  }
}

// ---------------- f32 -> bf16 elementwise convert (8 elems/thread) ----------------
__global__ __launch_bounds__(256) void cvt_f32_bf16(
    const float* __restrict__ in, __hip_bfloat16* __restrict__ out) {
  const long long i = ((long long)blockIdx.x * 256 + threadIdx.x) * 8;
  const float4 a = *(const float4*)(in + i);
  const float4 b = *(const float4*)(in + i + 4);
  u16x8 r;
  r[0] = f2bits(a.x); r[1] = f2bits(a.y); r[2] = f2bits(a.z); r[3] = f2bits(a.w);
  r[4] = f2bits(b.x); r[5] = f2bits(b.y); r[6] = f2bits(b.z); r[7] = f2bits(b.w);
  *(u16x8*)((unsigned short*)out + i) = r;
}

// ------------- 64x64 tiled transpose + f32->bf16 convert: out[c][r] = in[r][c] -------------
__global__ __launch_bounds__(256) void transpose_cvt_kernel(
    const float* __restrict__ in, __hip_bfloat16* __restrict__ out, int R, int C) {
  __shared__ unsigned short tile[64][65];
  const int c0 = blockIdx.x * 64, r0 = blockIdx.y * 64;
  const int tid = threadIdx.x;
  const int rr = tid >> 2, seg = (tid & 3) * 16;
  const float* src = in + (long long)(r0 + rr) * C + c0 + seg;
#pragma unroll
  for (int i = 0; i < 16; ++i) tile[rr][seg + i] = f2bits(src[i]);
  __syncthreads();
  unsigned short* dst = (unsigned short*)out + (long long)(c0 + rr) * R + r0 + seg;
#pragma unroll
  for (int i = 0; i < 16; ++i) dst[i] = tile[seg + i][rr];
}

// ---------------- 64x64 tiled bf16 transpose: out[c][r] = in[r][c] ----------------
__global__ __launch_bounds__(256) void transpose_kernel(
    const __hip_bfloat16* __restrict__ in, __hip_bfloat16* __restrict__ out,
    int R, int C) {
  __shared__ unsigned short tile[64][65];
  const long long slice = (long long)R * C;
  const unsigned short* ip = (const unsigned short*)in + (long long)blockIdx.z * slice;
  unsigned short* op = (unsigned short*)out + (long long)blockIdx.z * slice;
  const int c0 = blockIdx.x * 64, r0 = blockIdx.y * 64;
  const int tid = threadIdx.x;
  const int rr = tid >> 2, seg = (tid & 3) * 16;
  const unsigned short* src = ip + (long long)(r0 + rr) * C + c0 + seg;
#pragma unroll
  for (int i = 0; i < 16; ++i) tile[rr][seg + i] = src[i];
  __syncthreads();
  unsigned short* dst = op + (long long)(c0 + rr) * R + r0 + seg;
#pragma unroll
  for (int i = 0; i < 16; ++i) dst[i] = tile[seg + i][rr];
}

// ---------------- GEMM: C[m][n] = sum_k A[m][k]*Bt[n][k] (+bias[n]) ----------------
// A: MxK row-major bf16, Bt: NxK row-major bf16 (B pre-transposed), C: MxN (OT).
// 128x128 tile, 4 waves in 2x2, 4x4 16x16x32 MFMAs per wave.
// Round-10: BK=64 (halves barrier/drain events, 32 MFMA per stage) with the
// attn-proven ROWB=128 chunk-XOR swizzle on staging + reads (2-way banks = free);
// XCD-aware block swizzle (grid % 8 == 0 for both call sites -> bijective).
template <typename OT>
__global__ __launch_bounds__(256) void gemm_bt(
    const __hip_bfloat16* __restrict__ A, const __hip_bfloat16* __restrict__ Bt,
    const float* __restrict__ bias, OT* __restrict__ C, int M, int N, int K) {
  __shared__ __align__(16) char As[16384];  // 128 x 64 bf16 (chunk-swizzled)
  __shared__ __align__(16) char Bs[16384];
  // XCD-aware swizzle of the linearized block id (8 XCDs).
  const int nwgx = N >> 7;
  const int nwg = nwgx * (M >> 7);
  const int bid0 = blockIdx.y * nwgx + blockIdx.x;
  const int cpx = nwg >> 3;
  const int bid = (bid0 & 7) * cpx + (bid0 >> 3);
  const int n0 = (bid % nwgx) * 128;
  const int m0 = (bid / nwgx) * 128;
  const int tid = threadIdx.x;
  const int wid = tid >> 6, lane = tid & 63;
  const int wm = (wid >> 1) * 64, wn = (wid & 1) * 64;
  const int l15 = lane & 15, quad = lane >> 4;
  const int sw = l15 & 7;

  f32x4 acc[4][4] = {};

  const int nk = K >> 6;
  for (int kt = 0; kt < nk; ++kt) {
    __syncthreads();  // protect LDS reuse from previous iteration's readers
    stage_tile<128, 16384, true>((const char*)(A + (long long)m0 * K + kt * 64),
                                 (long long)K * 2, As);
    stage_tile<128, 16384, true>((const char*)(Bt + (long long)n0 * K + kt * 64),
                                 (long long)K * 2, Bs);
    __syncthreads();  // drains vmcnt(0): staging complete

#pragma unroll
    for (int kk = 0; kk < 2; ++kk) {
      FragU a[4], b[4];
#pragma unroll
      for (int mt = 0; mt < 4; ++mt)
        a[mt].u = *(const u16x8*)(As + (wm + mt * 16 + l15) * 128 +
                                  ((((kk << 2) | quad) ^ sw) << 4));
#pragma unroll
      for (int nt = 0; nt < 4; ++nt)
        b[nt].u = *(const u16x8*)(Bs + (wn + nt * 16 + l15) * 128 +
                                  ((((kk << 2) | quad) ^ sw) << 4));
#pragma unroll
      for (int mt = 0; mt < 4; ++mt)
#pragma unroll
        for (int nt = 0; nt < 4; ++nt)
          acc[mt][nt] =
              __builtin_amdgcn_mfma_f32_16x16x32_bf16(a[mt].b, b[nt].b, acc[mt][nt], 0, 0, 0);
    }
  }

#pragma unroll
  for (int nt = 0; nt < 4; ++nt) {
    const int col = n0 + wn + nt * 16 + l15;
    const float bv = bias ? bias[col] : 0.f;
#pragma unroll
    for (int mt = 0; mt < 4; ++mt) {
#pragma unroll
      for (int r = 0; r < 4; ++r) {
        const int row = m0 + wm + mt * 16 + quad * 4 + r;
        store_out(C + (long long)row * N + col, acc[mt][nt][r] + bv);
      }
    }
  }
}

// ---------------- RoPE + reshape (vectorized: one 16B chunk per thread) ----------------
// qkv (B*T, 3072) bf16 -> Q (B,H,T,64) roped*SCL, K (B,KVH,T,64) roped, V raw.
// SCL = (1/sqrt(64)) * log2(e) folded into Q so attention uses exp2.
// 384 threads/block, one row per block; thread t handles elems [8t, 8t+8) = 4 rope pairs.
__global__ __launch_bounds__(384) void rope_reshape(
    const __hip_bfloat16* __restrict__ qkv, const float* __restrict__ cosb,
    const float* __restrict__ sinb, __hip_bfloat16* __restrict__ Qo,
    __hip_bfloat16* __restrict__ Ko, __hip_bfloat16* __restrict__ Vo) {
  constexpr float SCL = 0.125f * 1.44269504088896f;
  const int row = blockIdx.x;            // b*T + t
  const int b = row / Tc, t = row % Tc;
  const unsigned short* src = (const unsigned short*)qkv + (long long)row * NQKV;
  const float* cb = cosb + t * 32;
  const float* sb = sinb + t * 32;
  const int e = (int)threadIdx.x * 8;    // 0..3064, section boundaries are multiples of 8
  const u16x8 v = *(const u16x8*)(src + e);
  if (e < Hc * HDc) {                         // Q section (scaled)
    const int hh = e >> 6, d = e & 63, ii = d >> 1;
    u16x8 r;
#pragma unroll
    for (int p = 0; p < 4; ++p) {
      const float c = cb[ii + p], s = sb[ii + p];
      const float xe = bits2f(v[2 * p]), xo = bits2f(v[2 * p + 1]);
      r[2 * p] = f2bits((xe * c - xo * s) * SCL);
      r[2 * p + 1] = f2bits((xe * s + xo * c) * SCL);
    }
    const long long idx = (((long long)b * Hc + hh) * Tc + t) * HDc + d;
    *(u16x8*)((unsigned short*)Qo + idx) = r;
  } else if (e < Hc * HDc + KVHc * HDc) {     // K section
    const int e2 = e - Hc * HDc;
    const int kh = e2 >> 6, d = e2 & 63, ii = d >> 1;
    u16x8 r;
#pragma unroll
    for (int p = 0; p < 4; ++p) {
      const float c = cb[ii + p], s = sb[ii + p];
      const float xe = bits2f(v[2 * p]), xo = bits2f(v[2 * p + 1]);
      r[2 * p] = f2bits(xe * c - xo * s);
      r[2 * p + 1] = f2bits(xe * s + xo * c);
    }
    const long long idx = (((long long)b * KVHc + kh) * Tc + t) * HDc + d;
    *(u16x8*)((unsigned short*)Ko + idx) = r;
  } else {                                    // V section (no rope)
    const int e2 = e - (Hc * HDc + KVHc * HDc);
    const int kh = e2 >> 6, d = e2 & 63;
    const long long idx = (((long long)b * KVHc + kh) * Tc + t) * HDc + d;
    *(u16x8*)((unsigned short*)Vo + idx) = v;
  }
}

// ---------------- attention helpers (round-6-proven math, refactored) ----------------
// Layouts: S^T strip: S[nt][r] has kv = nt*16+quad*4+r, q = wid*16+l15.
// Zero-shuffle PV: kv <-> mfma-k remapped identically on both operands as
// k = quad*8+j <-> kv = (2ks+(j>>2))*16 + quad*4 + (j&3).

DI void mask_diag(f32x4 (&S)[4], int wid, int l15, int quad) {
#pragma unroll
  for (int nt = 0; nt < 4; ++nt)
#pragma unroll
    for (int r = 0; r < 4; ++r)
      if ((nt * 16 + quad * 4 + r) > (wid * 16 + l15)) S[nt][r] = -1e30f;
}

// Online-softmax update (base 2) with DEFER-MAX (T13): when every lane's tile max
// grew by <= 8 over the running max, keep m_i and skip the O/l rescale entirely
// (P then bounded by 2^8 = 256 -- exact in bf16 range, fine for f32 accum).
// First tile always takes the full path (m_i = -1e30). Skip decision is wave-uniform
// (__all). Rescales O and l in place; consumes S (becomes P); packs PV B-fragments.
DI void softmax_update(f32x4 (&S)[4], f32x4 (&O)[4], float& m_i, float& l_i,
                       FragU (&pa)[2]) {
  float mx = fmaxf(fmaxf(S[0][0], S[0][1]), fmaxf(S[0][2], S[0][3]));
#pragma unroll
  for (int nt = 1; nt < 4; ++nt)
    mx = fmaxf(mx, fmaxf(fmaxf(S[nt][0], S[nt][1]), fmaxf(S[nt][2], S[nt][3])));
  mx = fmaxf(mx, __shfl_xor(mx, 16, 64));
  mx = fmaxf(mx, __shfl_xor(mx, 32, 64));
  if (!__all(mx <= m_i + 8.f)) {
    const float mnew = fmaxf(m_i, mx);
    const float alpha = EXP2(m_i - mnew);  // first tile: exp2(-inf) = 0
    m_i = mnew;
    l_i *= alpha;
#pragma unroll
    for (int nt = 0; nt < 4; ++nt)
#pragma unroll
      for (int r = 0; r < 4; ++r) O[nt][r] *= alpha;
  }
  float sum = 0.f;
#pragma unroll
  for (int nt = 0; nt < 4; ++nt)
#pragma unroll
    for (int r = 0; r < 4; ++r) {
      const float pp = EXP2(S[nt][r] - m_i);
      S[nt][r] = pp;
      sum += pp;
    }
  sum += __shfl_xor(sum, 16, 64);
  sum += __shfl_xor(sum, 32, 64);
  l_i += sum;
#pragma unroll
  for (int ks = 0; ks < 2; ++ks)
#pragma unroll
    for (int r = 0; r < 4; ++r) {
      pa[ks].u[r] = f2bits(S[2 * ks][r]);
      pa[ks].u[4 + r] = f2bits(S[2 * ks + 1][r]);
    }
}

// Single-state kv-tile (used when only q-state B is in causal range).
DI void attn_tile(const char* __restrict__ Ksb, const char* __restrict__ Vsb,
                  const FragU (&qa)[2], f32x4 (&O)[4], float& m_i, float& l_i,
                  bool diag, int wid, int l15, int quad, int sw) {
  f32x4 S[4] = {};
  __builtin_amdgcn_s_setprio(1);
#pragma unroll
  for (int nt = 0; nt < 4; ++nt) {
#pragma unroll
    for (int ks = 0; ks < 2; ++ks) {
      FragU kb;
      kb.u = *(const u16x8*)(Ksb + (nt * 16 + l15) * 128 + ((((ks << 2) | quad) ^ sw) << 4));
      S[nt] = __builtin_amdgcn_mfma_f32_16x16x32_bf16(kb.b, qa[ks].b, S[nt], 0, 0, 0);
    }
  }
  __builtin_amdgcn_s_setprio(0);
  if (diag) mask_diag(S, wid, l15, quad);
  FragU pa[2];
  softmax_update(S, O, m_i, l_i, pa);
  __builtin_amdgcn_s_setprio(1);
#pragma unroll
  for (int nt = 0; nt < 4; ++nt) {
    const char* vrow = Vsb + (nt * 16 + l15) * 128 + ((quad & 1) << 3);
    const int gq = quad >> 1;
#pragma unroll
    for (int ks = 0; ks < 2; ++ks) {
      FragU vb;
      vb.h[0] = *(const u16x4*)(vrow + (((ks * 4 + gq) ^ sw) << 4));
      vb.h[1] = *(const u16x4*)(vrow + (((ks * 4 + gq + 2) ^ sw) << 4));
      O[nt] = __builtin_amdgcn_mfma_f32_16x16x32_bf16(vb.b, pa[ks].b, O[nt], 0, 0, 0);
    }
  }
  __builtin_amdgcn_s_setprio(0);
}

// DUAL-state kv-tile (round-9): both q-states share every K/V fragment read
// (halves LDS traffic) and provide two independent dependence chains -> the
// scheduler pairs back-to-back MFMAs and overlaps the two softmax chains.
// B is never diagonal on the dual path (qtB > qtA always).
DI void attn_tile_dual(const char* __restrict__ Ksb, const char* __restrict__ Vsb,
                       const FragU (&qaB)[2], const FragU (&qaA)[2],
                       f32x4 (&OB)[4], f32x4 (&OA)[4],
                       float& mB, float& lB, float& mA, float& lA,
                       bool diagA, int wid, int l15, int quad, int sw) {
  f32x4 SB[4] = {}, SA[4] = {};
  __builtin_amdgcn_s_setprio(1);
#pragma unroll
  for (int nt = 0; nt < 4; ++nt) {
#pragma unroll
    for (int ks = 0; ks < 2; ++ks) {
      FragU kb;
      kb.u = *(const u16x8*)(Ksb + (nt * 16 + l15) * 128 + ((((ks << 2) | quad) ^ sw) << 4));
      SB[nt] = __builtin_amdgcn_mfma_f32_16x16x32_bf16(kb.b, qaB[ks].b, SB[nt], 0, 0, 0);
      SA[nt] = __builtin_amdgcn_mfma_f32_16x16x32_bf16(kb.b, qaA[ks].b, SA[nt], 0, 0, 0);
    }
  }
  __builtin_amdgcn_s_setprio(0);
  if (diagA) mask_diag(SA, wid, l15, quad);
  FragU paB[2], paA[2];
  softmax_update(SB, OB, mB, lB, paB);
  softmax_update(SA, OA, mA, lA, paA);
  __builtin_amdgcn_s_setprio(1);
#pragma unroll
  for (int nt = 0; nt < 4; ++nt) {
    const char* vrow = Vsb + (nt * 16 + l15) * 128 + ((quad & 1) << 3);
    const int gq = quad >> 1;
#pragma unroll
    for (int ks = 0; ks < 2; ++ks) {
      FragU vb;
      vb.h[0] = *(const u16x4*)(vrow + (((ks * 4 + gq) ^ sw) << 4));
      vb.h[1] = *(const u16x4*)(vrow + (((ks * 4 + gq + 2) ^ sw) << 4));
      OB[nt] = __builtin_amdgcn_mfma_f32_16x16x32_bf16(vb.b, paB[ks].b, OB[nt], 0, 0, 0);
      OA[nt] = __builtin_amdgcn_mfma_f32_16x16x32_bf16(vb.b, paA[ks].b, OA[nt], 0, 0, 0);
    }
  }
  __builtin_amdgcn_s_setprio(0);
}

// ------------- Causal flash attention, paired q-tiles + dual-state interleave -------------
// Q (B,H,T,64) pre-scaled by 0.125*log2e, K (B,KVH,T,64), Vt (B,KVH,64,T) -> Out (B,T,H*64).
// Block p handles q-tiles A=p, B=31-p: uniform 33 kv-tiles/block (round-7 balance).
// Q fragments direct from global (swizzle cancels; round-8). K/V double-buffered with
// top-of-loop prefetch + explicit vmcnt(0) drain + one barrier per tile (round-8).
// Dual-state fused tile on j <= qtA (round-9). Defer-max softmax (round-10).
__global__ __launch_bounds__(256, 4) void attn_kernel(
    const __hip_bfloat16* __restrict__ Q, const __hip_bfloat16* __restrict__ K,
    const __hip_bfloat16* __restrict__ Vt, __hip_bfloat16* __restrict__ Out) {
  __shared__ __align__(16) char Ks[2][8192];  // 64 kv x 64 hd (swizzled), double-buffered
  __shared__ __align__(16) char Vs[2][8192];  // 64 hd x 64 kv (swizzled), double-buffered

  const int p = blockIdx.x;                       // pair id 0..15
  const int qtA = p, qtB = (Tc / 64 - 1) - p;     // 31 - p
  const int h = blockIdx.y, b = blockIdx.z;
  const int kvh = h >> 2;  // G = 4
  const int tid = threadIdx.x, wid = tid >> 6, lane = tid & 63;
  const int l15 = lane & 15, quad = lane >> 4;
  const int sw = l15 & 7;

  const char* QgA = (const char*)(Q + (((long long)b * Hc + h) * Tc + qtA * 64) * HDc);
  const char* QgB = (const char*)(Q + (((long long)b * Hc + h) * Tc + qtB * 64) * HDc);
  const char* Kg = (const char*)(K + (((long long)b * KVHc + kvh) * Tc) * HDc);
  const char* Vg = (const char*)(Vt + (((long long)b * KVHc + kvh) * HDc) * Tc);

  // Q fragments straight from global: lane reads row (wid*16+l15), 16B chunk (ks*4+quad).
  FragU qaA[2], qaB[2];
#pragma unroll
  for (int ks = 0; ks < 2; ++ks) {
    const int qoff = (wid * 16 + l15) * 128 + (((ks << 2) | quad) << 4);
    qaA[ks].u = *(const u16x8*)(QgA + qoff);
    qaB[ks].u = *(const u16x8*)(QgB + qoff);
  }

  f32x4 OA[4] = {}, OB[4] = {};
  float mA = -1e30f, lA = 0.f, mB = -1e30f, lB = 0.f;

  // Prologue: stage tile 0 into buffer 0.
  stage_tile<128, 8192, true>(Kg, 128, Ks[0]);
  stage_tile<128, 8192, true>(Vg, (long long)Tc * 2, Vs[0]);
  asm volatile("s_waitcnt vmcnt(0)" ::: "memory");
  __syncthreads();

  for (int j = 0; j <= qtB; ++j) {
    const int cur = j & 1;
    // Prefetch next tile into the other buffer (released by last iter's barrier).
    if (j < qtB) {
      stage_tile<128, 8192, true>(Kg + (long long)(j + 1) * 8192, 128, Ks[cur ^ 1]);
      stage_tile<128, 8192, true>(Vg + (long long)(j + 1) * 128, (long long)Tc * 2, Vs[cur ^ 1]);
    }

    if (j <= qtA) {  // wave-uniform: A's kv range is a prefix of B's
      attn_tile_dual(Ks[cur], Vs[cur], qaB, qaA, OB, OA, mB, lB, mA, lA,
                     j == qtA, wid, l15, quad, sw);
    } else {
      attn_tile(Ks[cur], Vs[cur], qaB, OB, mB, lB, j == qtB, wid, l15, quad, sw);
    }

    asm volatile("s_waitcnt vmcnt(0)" ::: "memory");  // my prefetch landed in LDS
    __syncthreads();                                  // everyone's landed; buf[cur] released
  }

  // epilogue x2: O^T / l -> Out[b][t][h*64+hd]; r-contiguous -> 8B stores
  const float invA = 1.0f / lA, invB = 1.0f / lB;
  const int tA = qtA * 64 + wid * 16 + l15;
  const int tB = qtB * 64 + wid * 16 + l15;
  unsigned short* obA =
      (unsigned short*)Out + ((long long)b * Tc + tA) * Dc + h * 64 + quad * 4;
  unsigned short* obB =
      (unsigned short*)Out + ((long long)b * Tc + tB) * Dc + h * 64 + quad * 4;
#pragma unroll
  for (int nt = 0; nt < 4; ++nt) {
    u16x4 va, vb;
#pragma unroll
    for (int r = 0; r < 4; ++r) {
      va[r] = f2bits(OA[nt][r] * invA);
      vb[r] = f2bits(OB[nt][r] * invB);
    }
    *(u16x4*)(obA + nt * 16) = va;
    *(u16x4*)(obB + nt * 16) = vb;
  }
}

}  // namespace

extern "C" void kernel_launch(void* const* d_in, const int* in_sizes, int n_in,
                              void* d_out, int out_size, void* d_ws, size_t ws_size,
                              hipStream_t stream) {
  // All inputs/outputs are FLOAT32 per the reference dtypes.
  const float* x_q  = (const float*)d_in[0];
  const float* Wqkv = (const float*)d_in[1];
  const float* Wout = (const float*)d_in[2];
  const float* bout = (const float*)d_in[3];
  const float* rc   = (const float*)d_in[4];
  const float* rs   = (const float*)d_in[5];
  float* out = (float*)d_out;

  // ---- Overlapping bf16 workspace arena (peak 54.6 MB; stream order makes reuse safe) ----
  constexpr size_t SZ_QKV   = (size_t)Bc * Tc * NQKV * 2;        // 25,165,824
  constexpr size_t SZ_XB    = (size_t)Bc * Tc * Dc * 2;          // 16,777,216
  constexpr size_t SZ_QB    = (size_t)Bc * Hc * Tc * HDc * 2;    // 16,777,216
  constexpr size_t SZ_KV    = (size_t)Bc * KVHc * Tc * HDc * 2;  //  4,194,304
  constexpr size_t SZ_AO    = (size_t)Bc * Tc * Dc * 2;          // 16,777,216
  constexpr size_t OFF_QKV   = 0;                    //  0   .. 25.2M
  constexpr size_t OFF_XB    = SZ_QKV;               // 25.2 .. 41.9M
  constexpr size_t OFF_WQKVT = SZ_QKV + SZ_XB;       // 41.9 .. 54.6M
  constexpr size_t OFF_QB    = SZ_QKV;               // reuses xb (dead after G1)
  constexpr size_t OFF_KB    = OFF_QB + SZ_QB;       // reuses WqkvT head (dead after G1)
  constexpr size_t OFF_VTMP  = OFF_KB + SZ_KV;       // 46.1 .. 50.3M
  constexpr size_t OFF_VT    = 0;                    // reuses qkv (dead after R)
  constexpr size_t OFF_AO    = SZ_KV;                // 4.2 .. 21.0M (old qkv region)
  constexpr size_t OFF_WOUTT = OFF_AO + SZ_AO;       // 21.0 .. 29.4M (old Qb head, dead after A)

  char* w = (char*)d_ws;
  __hip_bfloat16* qkv   = (__hip_bfloat16*)(w + OFF_QKV);
  __hip_bfloat16* xb    = (__hip_bfloat16*)(w + OFF_XB);
  __hip_bfloat16* WqkvT = (__hip_bfloat16*)(w + OFF_WQKVT);
  __hip_bfloat16* Qb    = (__hip_bfloat16*)(w + OFF_QB);
  __hip_bfloat16* Kb    = (__hip_bfloat16*)(w + OFF_KB);
  __hip_bfloat16* Vtmp  = (__hip_bfloat16*)(w + OFF_VTMP);
  __hip_bfloat16* Vt    = (__hip_bfloat16*)(w + OFF_VT);
  __hip_bfloat16* AO    = (__hip_bfloat16*)(w + OFF_AO);
  __hip_bfloat16* WoutT = (__hip_bfloat16*)(w + OFF_WOUTT);

  // C1: x_q f32 -> bf16
  cvt_f32_bf16<<<dim3((Bc * Tc * Dc) / (256 * 8)), 256, 0, stream>>>(x_q, xb);

  // T1: W_qkv (D,3072) f32 -> (3072,D) bf16
  transpose_cvt_kernel<<<dim3(NQKV / 64, Dc / 64), 256, 0, stream>>>(Wqkv, WqkvT, Dc, NQKV);

  // G1: qkv = x @ W_qkv  (bf16 out)
  gemm_bt<__hip_bfloat16><<<dim3(NQKV / 128, (Bc * Tc) / 128), 256, 0, stream>>>(
      xb, WqkvT, nullptr, qkv, Bc * Tc, NQKV, Dc);

  // R: split + rope (+ Q pre-scale) + head-major layouts (384 thr = 3072/8 chunks)
  rope_reshape<<<dim3(Bc * Tc), 384, 0, stream>>>(qkv, rc, rs, Qb, Kb, Vtmp);

  // TV: V (B,KVH,T,64) -> V^T (B,KVH,64,T)
  transpose_kernel<<<dim3(HDc / 64, Tc / 64, Bc * KVHc), 256, 0, stream>>>(Vtmp, Vt, Tc, HDc);

  // A: flash attention (paired q-tiles, dual-state interleave, 2-phase K/V pipeline)
  attn_kernel<<<dim3(Tc / 128, Hc, Bc), 256, 0, stream>>>(Qb, Kb, Vt, AO);

  // T2: W_out f32 -> W_out^T bf16
  transpose_cvt_kernel<<<dim3(Dc / 64, Dc / 64), 256, 0, stream>>>(Wout, WoutT, Dc, Dc);

  // G2: out = AO @ W_out + b_out  (f32 out)
  gemm_bt<float><<<dim3(Dc / 128, (Bc * Tc) / 128), 256, 0, stream>>>(
      AO, WoutT, bout, out, Bc * Tc, Dc, Dc);
}

// Round 7
// 330.251 us; speedup vs baseline: 1.1376x; 1.0012x over previous
//
#include <hip/hip_runtime.h>
#include <hip/hip_bf16.h>

#define DI __device__ __forceinline__

#if __has_builtin(__builtin_amdgcn_exp2f)
#define EXP2(x) __builtin_amdgcn_exp2f(x)
#else
#define EXP2(x) exp2f(x)
#endif

namespace {

constexpr int Bc = 2, Tc = 2048, Dc = 2048, Hc = 32, KVHc = 8, HDc = 64;
constexpr int NQKV = Hc * HDc + 2 * KVHc * HDc;  // 3072

typedef __bf16 bf16x8 __attribute__((ext_vector_type(8)));
typedef unsigned short u16x8 __attribute__((ext_vector_type(8)));
typedef unsigned short u16x4 __attribute__((ext_vector_type(4)));
typedef float f32x4 __attribute__((ext_vector_type(4)));

union FragU { u16x8 u; bf16x8 b; u16x4 h[2]; };

DI float bits2f(unsigned int u) {
  union { unsigned int i; float f; } v; v.i = u << 16; return v.f;
}
DI unsigned short f2bits(float f) {
  __hip_bfloat16 h = __float2bfloat16(f);
  return *reinterpret_cast<unsigned short*>(&h);
}

DI void store_out(float* p, float v) { *p = v; }
DI void store_out(__hip_bfloat16* p, float v) { *p = __float2bfloat16(v); }

typedef __attribute__((address_space(1))) void gv_t;
typedef __attribute__((address_space(3))) void lv_t;

// Stage TOTB bytes (tile rows of ROWB bytes, global row stride row_stride_b) into
// LDS via global_load_lds width=16. LDS dest is wave-uniform base + lane*16 (HW),
// so the optional XOR swizzle permutes the GLOBAL source chunk per lane instead:
// LDS slot (row, chunk k) holds global chunk k ^ (row&7)  [ROWB=128 only].
template<int ROWB, int TOTB, bool SWZ = false>
DI void stage_tile(const char* g, long long row_stride_b, char* lds) {
  const int tid = threadIdx.x;
  const int wid = tid >> 6, lane = tid & 63;
#pragma unroll
  for (int it = 0; it < TOTB / 4096; ++it) {
    int off = it * 4096 + wid * 1024 + lane * 16;
    int row = off / ROWB;
    int colb = off % ROWB;
    if (SWZ) colb ^= (row & 7) << 4;  // 16B-chunk XOR swizzle (ROWB=128)
    const char* gp = g + (long long)row * row_stride_b + colb;
    char* lp = lds + it * 4096 + wid * 1024;  // wave-uniform
    __builtin_amdgcn_global_load_lds((gv_t*)gp, (lv_t*)lp, 16, 0, 0);
  }
}

// ---------------- f32 -> bf16 elementwise convert (8 elems/thread) ----------------
__global__ __launch_bounds__(256) void cvt_f32_bf16(
    const float* __restrict__ in, __hip_bfloat16* __restrict__ out) {
  const long long i = ((long long)blockIdx.x * 256 + threadIdx.x) * 8;
  const float4 a = *(const float4*)(in + i);
  const float4 b = *(const float4*)(in + i + 4);
  u16x8 r;
  r[0] = f2bits(a.x); r[1] = f2bits(a.y); r[2] = f2bits(a.z); r[3] = f2bits(a.w);
  r[4] = f2bits(b.x); r[5] = f2bits(b.y); r[6] = f2bits(b.z); r[7] = f2bits(b.w);
  *(u16x8*)((unsigned short*)out + i) = r;
}

// ------------- 64x64 tiled transpose + f32->bf16 convert: out[c][r] = in[r][c] -------------
__global__ __launch_bounds__(256) void transpose_cvt_kernel(
    const float* __restrict__ in, __hip_bfloat16* __restrict__ out, int R, int C) {
  __shared__ unsigned short tile[64][65];
  const int c0 = blockIdx.x * 64, r0 = blockIdx.y * 64;
  const int tid = threadIdx.x;
  const int rr = tid >> 2, seg = (tid & 3) * 16;
  const float* src = in + (long long)(r0 + rr) * C + c0 + seg;
#pragma unroll
  for (int i = 0; i < 16; ++i) tile[rr][seg + i] = f2bits(src[i]);
  __syncthreads();
  unsigned short* dst = (unsigned short*)out + (long long)(c0 + rr) * R + r0 + seg;
#pragma unroll
  for (int i = 0; i < 16; ++i) dst[i] = tile[seg + i][rr];
}

// ---------------- 64x64 tiled bf16 transpose: out[c][r] = in[r][c] ----------------
__global__ __launch_bounds__(256) void transpose_kernel(
    const __hip_bfloat16* __restrict__ in, __hip_bfloat16* __restrict__ out,
    int R, int C) {
  __shared__ unsigned short tile[64][65];
  const long long slice = (long long)R * C;
  const unsigned short* ip = (const unsigned short*)in + (long long)blockIdx.z * slice;
  unsigned short* op = (unsigned short*)out + (long long)blockIdx.z * slice;
  const int c0 = blockIdx.x * 64, r0 = blockIdx.y * 64;
  const int tid = threadIdx.x;
  const int rr = tid >> 2, seg = (tid & 3) * 16;
  const unsigned short* src = ip + (long long)(r0 + rr) * C + c0 + seg;
#pragma unroll
  for (int i = 0; i < 16; ++i) tile[rr][seg + i] = src[i];
  __syncthreads();
  unsigned short* dst = op + (long long)(c0 + rr) * R + r0 + seg;
#pragma unroll
  for (int i = 0; i < 16; ++i) dst[i] = tile[seg + i][rr];
}

// ---------------- GEMM: C[m][n] = sum_k A[m][k]*Bt[n][k] (+bias[n]) ----------------
// A: MxK row-major bf16, Bt: NxK row-major bf16 (B pre-transposed), C: MxN (OT).
// 128x128 tile, BK=32, 4 waves in 2x2, 4x4 16x16x32 MFMAs per wave.
// Round-11: counted-vmcnt pipeline (T4). K/V double-buffered LDS (32 KB, 5 blocks/CU);
// fills issued 2 iterations ahead; raw s_barrier + s_waitcnt vmcnt(4) (waits ONLY for
// the tile about to be computed -- next tile's 4 loads stay in flight across both
// barriers; never drains to 0 in the main loop). lgkm is drained implicitly: every
// ds_read feeds an MFMA before barrier-2 (compiler use-waits); sched_barrier(0) pins
// ordering. Last iteration uses vmcnt(0). XCD-aware block swizzle kept (grids % 8 == 0).
template <typename OT>
__global__ __launch_bounds__(256) void gemm_bt(
    const __hip_bfloat16* __restrict__ A, const __hip_bfloat16* __restrict__ Bt,
    const float* __restrict__ bias, OT* __restrict__ C, int M, int N, int K) {
  __shared__ __align__(16) char As[2][8192];  // 128 x 32 bf16, double-buffered
  __shared__ __align__(16) char Bs[2][8192];
  // XCD-aware swizzle of the linearized block id (8 XCDs; nwg % 8 == 0 -> bijective).
  const int nwgx = N >> 7;
  const int nwg = nwgx * (M >> 7);
  const int bid0 = blockIdx.y * nwgx + blockIdx.x;
  const int cpx = nwg >> 3;
  const int bid = (bid0 & 7) * cpx + (bid0 >> 3);
  const int n0 = (bid % nwgx) * 128;
  const int m0 = (bid / nwgx) * 128;
  const int tid = threadIdx.x;
  const int wid = tid >> 6, lane = tid & 63;
  const int wm = (wid >> 1) * 64, wn = (wid & 1) * 64;
  const int l15 = lane & 15, quad = lane >> 4;

  const char* Ag = (const char*)(A + (long long)m0 * K);
  const char* Bg = (const char*)(Bt + (long long)n0 * K);
  const long long strb = (long long)K * 2;

  f32x4 acc[4][4] = {};
  const int nk = K >> 5;

  // Prologue: fill both buffers (8 loads/thread outstanding).
  stage_tile<64, 8192>(Ag, strb, As[0]);
  stage_tile<64, 8192>(Bg, strb, Bs[0]);
  stage_tile<64, 8192>(Ag + 64, strb, As[1]);
  stage_tile<64, 8192>(Bg + 64, strb, Bs[1]);

  for (int kt = 0; kt < nk; ++kt) {
    // Wait for fill(kt) only: 4 newer loads (fill kt+1) may stay in flight.
    if (kt < nk - 1) asm volatile("s_waitcnt vmcnt(4)" ::: "memory");
    else             asm volatile("s_waitcnt vmcnt(0)" ::: "memory");
    __builtin_amdgcn_sched_barrier(0);
    __builtin_amdgcn_s_barrier();  // all waves' fill(kt) landed
    __builtin_amdgcn_sched_barrier(0);

    const char* as = As[kt & 1];
    const char* bs = Bs[kt & 1];
    FragU a[4], b[4];
#pragma unroll
    for (int mt = 0; mt < 4; ++mt)
      a[mt].u = *(const u16x8*)(as + ((wm + mt * 16 + l15) * 32 + quad * 8) * 2);
#pragma unroll
    for (int nt = 0; nt < 4; ++nt)
      b[nt].u = *(const u16x8*)(bs + ((wn + nt * 16 + l15) * 32 + quad * 8) * 2);
#pragma unroll
    for (int mt = 0; mt < 4; ++mt)
#pragma unroll
      for (int nt = 0; nt < 4; ++nt)
        acc[mt][nt] =
            __builtin_amdgcn_mfma_f32_16x16x32_bf16(a[mt].b, b[nt].b, acc[mt][nt], 0, 0, 0);

    __builtin_amdgcn_sched_barrier(0);
    __builtin_amdgcn_s_barrier();  // all waves done reading buf(kt&1)
    __builtin_amdgcn_sched_barrier(0);
    if (kt + 2 < nk) {  // refill the buffer just released
      stage_tile<64, 8192>(Ag + (long long)(kt + 2) * 64, strb, As[kt & 1]);
      stage_tile<64, 8192>(Bg + (long long)(kt + 2) * 64, strb, Bs[kt & 1]);
    }
  }

#pragma unroll
  for (int nt = 0; nt < 4; ++nt) {
    const int col = n0 + wn + nt * 16 + l15;
    const float bv = bias ? bias[col] : 0.f;
#pragma unroll
    for (int mt = 0; mt < 4; ++mt) {
#pragma unroll
      for (int r = 0; r < 4; ++r) {
        const int row = m0 + wm + mt * 16 + quad * 4 + r;
        store_out(C + (long long)row * N + col, acc[mt][nt][r] + bv);
      }
    }
  }
}

// ---------------- RoPE + reshape (vectorized: one 16B chunk per thread) ----------------
// qkv (B*T, 3072) bf16 -> Q (B,H,T,64) roped*SCL, K (B,KVH,T,64) roped, V raw.
// SCL = (1/sqrt(64)) * log2(e) folded into Q so attention uses exp2.
// 384 threads/block, one row per block; thread t handles elems [8t, 8t+8) = 4 rope pairs.
__global__ __launch_bounds__(384) void rope_reshape(
    const __hip_bfloat16* __restrict__ qkv, const float* __restrict__ cosb,
    const float* __restrict__ sinb, __hip_bfloat16* __restrict__ Qo,
    __hip_bfloat16* __restrict__ Ko, __hip_bfloat16* __restrict__ Vo) {
  constexpr float SCL = 0.125f * 1.44269504088896f;
  const int row = blockIdx.x;            // b*T + t
  const int b = row / Tc, t = row % Tc;
  const unsigned short* src = (const unsigned short*)qkv + (long long)row * NQKV;
  const float* cb = cosb + t * 32;
  const float* sb = sinb + t * 32;
  const int e = (int)threadIdx.x * 8;    // 0..3064, section boundaries are multiples of 8
  const u16x8 v = *(const u16x8*)(src + e);
  if (e < Hc * HDc) {                         // Q section (scaled)
    const int hh = e >> 6, d = e & 63, ii = d >> 1;
    u16x8 r;
#pragma unroll
    for (int p = 0; p < 4; ++p) {
      const float c = cb[ii + p], s = sb[ii + p];
      const float xe = bits2f(v[2 * p]), xo = bits2f(v[2 * p + 1]);
      r[2 * p] = f2bits((xe * c - xo * s) * SCL);
      r[2 * p + 1] = f2bits((xe * s + xo * c) * SCL);
    }
    const long long idx = (((long long)b * Hc + hh) * Tc + t) * HDc + d;
    *(u16x8*)((unsigned short*)Qo + idx) = r;
  } else if (e < Hc * HDc + KVHc * HDc) {     // K section
    const int e2 = e - Hc * HDc;
    const int kh = e2 >> 6, d = e2 & 63, ii = d >> 1;
    u16x8 r;
#pragma unroll
    for (int p = 0; p < 4; ++p) {
      const float c = cb[ii + p], s = sb[ii + p];
      const float xe = bits2f(v[2 * p]), xo = bits2f(v[2 * p + 1]);
      r[2 * p] = f2bits(xe * c - xo * s);
      r[2 * p + 1] = f2bits(xe * s + xo * c);
    }
    const long long idx = (((long long)b * KVHc + kh) * Tc + t) * HDc + d;
    *(u16x8*)((unsigned short*)Ko + idx) = r;
  } else {                                    // V section (no rope)
    const int e2 = e - (Hc * HDc + KVHc * HDc);
    const int kh = e2 >> 6, d = e2 & 63;
    const long long idx = (((long long)b * KVHc + kh) * Tc + t) * HDc + d;
    *(u16x8*)((unsigned short*)Vo + idx) = v;
  }
}

// ---------------- attention helpers (round-9-proven; defer-max reverted) ----------------
// Layouts: S^T strip: S[nt][r] has kv = nt*16+quad*4+r, q = wid*16+l15.
// Zero-shuffle PV: kv <-> mfma-k remapped identically on both operands as
// k = quad*8+j <-> kv = (2ks+(j>>2))*16 + quad*4 + (j&3).

DI void mask_diag(f32x4 (&S)[4], int wid, int l15, int quad) {
#pragma unroll
  for (int nt = 0; nt < 4; ++nt)
#pragma unroll
    for (int r = 0; r < 4; ++r)
      if ((nt * 16 + quad * 4 + r) > (wid * 16 + l15)) S[nt][r] = -1e30f;
}

// Online-softmax update (base 2): consumes S in place (becomes p), returns alpha,
// updates m,l, and packs the PV B-fragments (lane-local, zero data movement).
DI float softmax_pack(f32x4 (&S)[4], float& m_i, float& l_i, FragU (&pa)[2]) {
  float mx = fmaxf(fmaxf(S[0][0], S[0][1]), fmaxf(S[0][2], S[0][3]));
#pragma unroll
  for (int nt = 1; nt < 4; ++nt)
    mx = fmaxf(mx, fmaxf(fmaxf(S[nt][0], S[nt][1]), fmaxf(S[nt][2], S[nt][3])));
  mx = fmaxf(mx, __shfl_xor(mx, 16, 64));
  mx = fmaxf(mx, __shfl_xor(mx, 32, 64));
  const float mnew = fmaxf(m_i, mx);
  const float alpha = EXP2(m_i - mnew);  // first tile: exp2(-inf) = 0
  m_i = mnew;
  float sum = 0.f;
#pragma unroll
  for (int nt = 0; nt < 4; ++nt)
#pragma unroll
    for (int r = 0; r < 4; ++r) {
      const float pp = EXP2(S[nt][r] - mnew);
      S[nt][r] = pp;
      sum += pp;
    }
  sum += __shfl_xor(sum, 16, 64);
  sum += __shfl_xor(sum, 32, 64);
  l_i = l_i * alpha + sum;
#pragma unroll
  for (int ks = 0; ks < 2; ++ks)
#pragma unroll
    for (int r = 0; r < 4; ++r) {
      pa[ks].u[r] = f2bits(S[2 * ks][r]);
      pa[ks].u[4 + r] = f2bits(S[2 * ks + 1][r]);
    }
  return alpha;
}

// Single-state kv-tile (used when only q-state B is in causal range).
DI void attn_tile(const char* __restrict__ Ksb, const char* __restrict__ Vsb,
                  const FragU (&qa)[2], f32x4 (&O)[4], float& m_i, float& l_i,
                  bool diag, int wid, int l15, int quad, int sw) {
  f32x4 S[4] = {};
  __builtin_amdgcn_s_setprio(1);
#pragma unroll
  for (int nt = 0; nt < 4; ++nt) {
#pragma unroll
    for (int ks = 0; ks < 2; ++ks) {
      FragU kb;
      kb.u = *(const u16x8*)(Ksb + (nt * 16 + l15) * 128 + ((((ks << 2) | quad) ^ sw) << 4));
      S[nt] = __builtin_amdgcn_mfma_f32_16x16x32_bf16(kb.b, qa[ks].b, S[nt], 0, 0, 0);
    }
  }
  __builtin_amdgcn_s_setprio(0);
  if (diag) mask_diag(S, wid, l15, quad);
  FragU pa[2];
  const float alpha = softmax_pack(S, m_i, l_i, pa);
#pragma unroll
  for (int nt = 0; nt < 4; ++nt)
#pragma unroll
    for (int r = 0; r < 4; ++r) O[nt][r] *= alpha;
  __builtin_amdgcn_s_setprio(1);
#pragma unroll
  for (int nt = 0; nt < 4; ++nt) {
    const char* vrow = Vsb + (nt * 16 + l15) * 128 + ((quad & 1) << 3);
    const int gq = quad >> 1;
#pragma unroll
    for (int ks = 0; ks < 2; ++ks) {
      FragU vb;
      vb.h[0] = *(const u16x4*)(vrow + (((ks * 4 + gq) ^ sw) << 4));
      vb.h[1] = *(const u16x4*)(vrow + (((ks * 4 + gq + 2) ^ sw) << 4));
      O[nt] = __builtin_amdgcn_mfma_f32_16x16x32_bf16(vb.b, pa[ks].b, O[nt], 0, 0, 0);
    }
  }
  __builtin_amdgcn_s_setprio(0);
}

// DUAL-state kv-tile (round-9): both q-states share every K/V fragment read
// (halves LDS traffic) and provide two independent dependence chains -> the
// scheduler pairs back-to-back MFMAs and overlaps the two softmax chains.
// B is never diagonal on the dual path (qtB > qtA always).
DI void attn_tile_dual(const char* __restrict__ Ksb, const char* __restrict__ Vsb,
                       const FragU (&qaB)[2], const FragU (&qaA)[2],
                       f32x4 (&OB)[4], f32x4 (&OA)[4],
                       float& mB, float& lB, float& mA, float& lA,
                       bool diagA, int wid, int l15, int quad, int sw) {
  f32x4 SB[4] = {}, SA[4] = {};
  __builtin_amdgcn_s_setprio(1);
#pragma unroll
  for (int nt = 0; nt < 4; ++nt) {
#pragma unroll
    for (int ks = 0; ks < 2; ++ks) {
      FragU kb;
      kb.u = *(const u16x8*)(Ksb + (nt * 16 + l15) * 128 + ((((ks << 2) | quad) ^ sw) << 4));
      SB[nt] = __builtin_amdgcn_mfma_f32_16x16x32_bf16(kb.b, qaB[ks].b, SB[nt], 0, 0, 0);
      SA[nt] = __builtin_amdgcn_mfma_f32_16x16x32_bf16(kb.b, qaA[ks].b, SA[nt], 0, 0, 0);
    }
  }
  __builtin_amdgcn_s_setprio(0);
  if (diagA) mask_diag(SA, wid, l15, quad);
  FragU paB[2], paA[2];
  const float aB = softmax_pack(SB, mB, lB, paB);
  const float aA = softmax_pack(SA, mA, lA, paA);
#pragma unroll
  for (int nt = 0; nt < 4; ++nt)
#pragma unroll
    for (int r = 0; r < 4; ++r) {
      OB[nt][r] *= aB;
      OA[nt][r] *= aA;
    }
  __builtin_amdgcn_s_setprio(1);
#pragma unroll
  for (int nt = 0; nt < 4; ++nt) {
    const char* vrow = Vsb + (nt * 16 + l15) * 128 + ((quad & 1) << 3);
    const int gq = quad >> 1;
#pragma unroll
    for (int ks = 0; ks < 2; ++ks) {
      FragU vb;
      vb.h[0] = *(const u16x4*)(vrow + (((ks * 4 + gq) ^ sw) << 4));
      vb.h[1] = *(const u16x4*)(vrow + (((ks * 4 + gq + 2) ^ sw) << 4));
      OB[nt] = __builtin_amdgcn_mfma_f32_16x16x32_bf16(vb.b, paB[ks].b, OB[nt], 0, 0, 0);
      OA[nt] = __builtin_amdgcn_mfma_f32_16x16x32_bf16(vb.b, paA[ks].b, OA[nt], 0, 0, 0);
    }
  }
  __builtin_amdgcn_s_setprio(0);
}

// ------------- Causal flash attention, paired q-tiles + dual-state interleave -------------
// Q (B,H,T,64) pre-scaled by 0.125*log2e, K (B,KVH,T,64), Vt (B,KVH,64,T) -> Out (B,T,H*64).
// Block p handles q-tiles A=p, B=31-p: uniform 33 kv-tiles/block (round-7 balance).
// Q fragments direct from global (swizzle cancels; round-8). K/V double-buffered with
// top-of-loop prefetch + explicit vmcnt(0) drain + one barrier per tile (round-8).
// Dual-state fused tile on j <= qtA (round-9). [round-10 defer-max reverted: neutral]
__global__ __launch_bounds__(256, 4) void attn_kernel(
    const __hip_bfloat16* __restrict__ Q, const __hip_bfloat16* __restrict__ K,
    const __hip_bfloat16* __restrict__ Vt, __hip_bfloat16* __restrict__ Out) {
  __shared__ __align__(16) char Ks[2][8192];  // 64 kv x 64 hd (swizzled), double-buffered
  __shared__ __align__(16) char Vs[2][8192];  // 64 hd x 64 kv (swizzled), double-buffered

  const int p = blockIdx.x;                       // pair id 0..15
  const int qtA = p, qtB = (Tc / 64 - 1) - p;     // 31 - p
  const int h = blockIdx.y, b = blockIdx.z;
  const int kvh = h >> 2;  // G = 4
  const int tid = threadIdx.x, wid = tid >> 6, lane = tid & 63;
  const int l15 = lane & 15, quad = lane >> 4;
  const int sw = l15 & 7;

  const char* QgA = (const char*)(Q + (((long long)b * Hc + h) * Tc + qtA * 64) * HDc);
  const char* QgB = (const char*)(Q + (((long long)b * Hc + h) * Tc + qtB * 64) * HDc);
  const char* Kg = (const char*)(K + (((long long)b * KVHc + kvh) * Tc) * HDc);
  const char* Vg = (const char*)(Vt + (((long long)b * KVHc + kvh) * HDc) * Tc);

  // Q fragments straight from global: lane reads row (wid*16+l15), 16B chunk (ks*4+quad).
  FragU qaA[2], qaB[2];
#pragma unroll
  for (int ks = 0; ks < 2; ++ks) {
    const int qoff = (wid * 16 + l15) * 128 + (((ks << 2) | quad) << 4);
    qaA[ks].u = *(const u16x8*)(QgA + qoff);
    qaB[ks].u = *(const u16x8*)(QgB + qoff);
  }

  f32x4 OA[4] = {}, OB[4] = {};
  float mA = -1e30f, lA = 0.f, mB = -1e30f, lB = 0.f;

  // Prologue: stage tile 0 into buffer 0.
  stage_tile<128, 8192, true>(Kg, 128, Ks[0]);
  stage_tile<128, 8192, true>(Vg, (long long)Tc * 2, Vs[0]);
  asm volatile("s_waitcnt vmcnt(0)" ::: "memory");
  __syncthreads();

  for (int j = 0; j <= qtB; ++j) {
    const int cur = j & 1;
    // Prefetch next tile into the other buffer (released by last iter's barrier).
    if (j < qtB) {
      stage_tile<128, 8192, true>(Kg + (long long)(j + 1) * 8192, 128, Ks[cur ^ 1]);
      stage_tile<128, 8192, true>(Vg + (long long)(j + 1) * 128, (long long)Tc * 2, Vs[cur ^ 1]);
    }

    if (j <= qtA) {  // wave-uniform: A's kv range is a prefix of B's
      attn_tile_dual(Ks[cur], Vs[cur], qaB, qaA, OB, OA, mB, lB, mA, lA,
                     j == qtA, wid, l15, quad, sw);
    } else {
      attn_tile(Ks[cur], Vs[cur], qaB, OB, mB, lB, j == qtB, wid, l15, quad, sw);
    }

    asm volatile("s_waitcnt vmcnt(0)" ::: "memory");  // my prefetch landed in LDS
    __syncthreads();                                  // everyone's landed; buf[cur] released
  }

  // epilogue x2: O^T / l -> Out[b][t][h*64+hd]; r-contiguous -> 8B stores
  const float invA = 1.0f / lA, invB = 1.0f / lB;
  const int tA = qtA * 64 + wid * 16 + l15;
  const int tB = qtB * 64 + wid * 16 + l15;
  unsigned short* obA =
      (unsigned short*)Out + ((long long)b * Tc + tA) * Dc + h * 64 + quad * 4;
  unsigned short* obB =
      (unsigned short*)Out + ((long long)b * Tc + tB) * Dc + h * 64 + quad * 4;
#pragma unroll
  for (int nt = 0; nt < 4; ++nt) {
    u16x4 va, vb;
#pragma unroll
    for (int r = 0; r < 4; ++r) {
      va[r] = f2bits(OA[nt][r] * invA);
      vb[r] = f2bits(OB[nt][r] * invB);
    }
    *(u16x4*)(obA + nt * 16) = va;
    *(u16x4*)(obB + nt * 16) = vb;
  }
}

}  // namespace

extern "C" void kernel_launch(void* const* d_in, const int* in_sizes, int n_in,
                              void* d_out, int out_size, void* d_ws, size_t ws_size,
                              hipStream_t stream) {
  // All inputs/outputs are FLOAT32 per the reference dtypes.
  const float* x_q  = (const float*)d_in[0];
  const float* Wqkv = (const float*)d_in[1];
  const float* Wout = (const float*)d_in[2];
  const float* bout = (const float*)d_in[3];
  const float* rc   = (const float*)d_in[4];
  const float* rs   = (const float*)d_in[5];
  float* out = (float*)d_out;

  // ---- Overlapping bf16 workspace arena (peak 54.6 MB; stream order makes reuse safe) ----
  constexpr size_t SZ_QKV   = (size_t)Bc * Tc * NQKV * 2;        // 25,165,824
  constexpr size_t SZ_XB    = (size_t)Bc * Tc * Dc * 2;          // 16,777,216
  constexpr size_t SZ_QB    = (size_t)Bc * Hc * Tc * HDc * 2;    // 16,777,216
  constexpr size_t SZ_KV    = (size_t)Bc * KVHc * Tc * HDc * 2;  //  4,194,304
  constexpr size_t SZ_AO    = (size_t)Bc * Tc * Dc * 2;          // 16,777,216
  constexpr size_t OFF_QKV   = 0;                    //  0   .. 25.2M
  constexpr size_t OFF_XB    = SZ_QKV;               // 25.2 .. 41.9M
  constexpr size_t OFF_WQKVT = SZ_QKV + SZ_XB;       // 41.9 .. 54.6M
  constexpr size_t OFF_QB    = SZ_QKV;               // reuses xb (dead after G1)
  constexpr size_t OFF_KB    = OFF_QB + SZ_QB;       // reuses WqkvT head (dead after G1)
  constexpr size_t OFF_VTMP  = OFF_KB + SZ_KV;       // 46.1 .. 50.3M
  constexpr size_t OFF_VT    = 0;                    // reuses qkv (dead after R)
  constexpr size_t OFF_AO    = SZ_KV;                // 4.2 .. 21.0M (old qkv region)
  constexpr size_t OFF_WOUTT = OFF_AO + SZ_AO;       // 21.0 .. 29.4M (old Qb head, dead after A)

  char* w = (char*)d_ws;
  __hip_bfloat16* qkv   = (__hip_bfloat16*)(w + OFF_QKV);
  __hip_bfloat16* xb    = (__hip_bfloat16*)(w + OFF_XB);
  __hip_bfloat16* WqkvT = (__hip_bfloat16*)(w + OFF_WQKVT);
  __hip_bfloat16* Qb    = (__hip_bfloat16*)(w + OFF_QB);
  __hip_bfloat16* Kb    = (__hip_bfloat16*)(w + OFF_KB);
  __hip_bfloat16* Vtmp  = (__hip_bfloat16*)(w + OFF_VTMP);
  __hip_bfloat16* Vt    = (__hip_bfloat16*)(w + OFF_VT);
  __hip_bfloat16* AO    = (__hip_bfloat16*)(w + OFF_AO);
  __hip_bfloat16* WoutT = (__hip_bfloat16*)(w + OFF_WOUTT);

  // C1: x_q f32 -> bf16
  cvt_f32_bf16<<<dim3((Bc * Tc * Dc) / (256 * 8)), 256, 0, stream>>>(x_q, xb);

  // T1: W_qkv (D,3072) f32 -> (3072,D) bf16
  transpose_cvt_kernel<<<dim3(NQKV / 64, Dc / 64), 256, 0, stream>>>(Wqkv, WqkvT, Dc, NQKV);

  // G1: qkv = x @ W_qkv  (bf16 out)
  gemm_bt<__hip_bfloat16><<<dim3(NQKV / 128, (Bc * Tc) / 128), 256, 0, stream>>>(
      xb, WqkvT, nullptr, qkv, Bc * Tc, NQKV, Dc);

  // R: split + rope (+ Q pre-scale) + head-major layouts (384 thr = 3072/8 chunks)
  rope_reshape<<<dim3(Bc * Tc), 384, 0, stream>>>(qkv, rc, rs, Qb, Kb, Vtmp);

  // TV: V (B,KVH,T,64) -> V^T (B,KVH,64,T)
  transpose_kernel<<<dim3(HDc / 64, Tc / 64, Bc * KVHc), 256, 0, stream>>>(Vtmp, Vt, Tc, HDc);

  // A: flash attention (paired q-tiles, dual-state interleave, 2-phase K/V pipeline)
  attn_kernel<<<dim3(Tc / 128, Hc, Bc), 256, 0, stream>>>(Qb, Kb, Vt, AO);

  // T2: W_out f32 -> W_out^T bf16
  transpose_cvt_kernel<<<dim3(Dc / 64, Dc / 64), 256, 0, stream>>>(Wout, WoutT, Dc, Dc);

  // G2: out = AO @ W_out + b_out  (f32 out)
  gemm_bt<float><<<dim3(Dc / 128, (Bc * Tc) / 128), 256, 0, stream>>>(
      AO, WoutT, bout, out, Bc * Tc, Dc, Dc);
}